// Round 10
// baseline (647.655 us; speedup 1.0000x reference)
//
#include <hip/hip_runtime.h>
#include <stdint.h>
#include <stdio.h>

#define T_TOK 4096
#define DMODEL 2048
#define NEXP 8
#define DFF 1408
#define DFFS 2816
#define NSLOT 8192   // T_TOK * 2

// XCD-interleaved schedule tables: idx = pos*8 + xcd; sentinel-padded.
#define GU_PXL 120
#define DN_PXL 96
#define GU_GRID (8 * GU_PXL)   // 960 (worst-case live blocks <= 781)
#define DN_GRID (8 * DN_PXL)   // 768 (worst-case live blocks <= 440)
#define SENTINEL 0x7FFFFFFF

typedef unsigned short u16;
typedef short s16x8 __attribute__((ext_vector_type(8)));
typedef unsigned short u16x4 __attribute__((ext_vector_type(4)));
typedef __bf16 bf16x8 __attribute__((ext_vector_type(8)));
typedef float f32x4 __attribute__((ext_vector_type(4)));

__device__ __forceinline__ u16 f2bf(float f) {
  uint32_t u = __builtin_bit_cast(uint32_t, f);
  u += 0x7fffu + ((u >> 16) & 1u);
  return (u16)(u >> 16);
}
__device__ __forceinline__ float bf2f(u16 h) {
  uint32_t u = ((uint32_t)h) << 16;
  return __builtin_bit_cast(float, u);
}

// async global->LDS, 16B per lane; LDS dest = wave-uniform base + lane*16
__device__ __forceinline__ void gl16(const u16* g, u16* l) {
  __builtin_amdgcn_global_load_lds((const __attribute__((address_space(1))) void*)g,
                                   (__attribute__((address_space(3))) void*)l,
                                   16, 0, 0);
}

#define BARRIER() asm volatile("s_barrier" ::: "memory")
#define SBAR()    __builtin_amdgcn_sched_barrier(0)

// ---------------- merged fp32 -> bf16 convert (grid-stride, 8 elems/iter) ----------------
__global__ void k_convert6(const float* __restrict__ s0, u16* __restrict__ d0, int n0,
                           const float* __restrict__ s1, u16* __restrict__ d1, int n1,
                           const float* __restrict__ s2, u16* __restrict__ d2, int n2,
                           const float* __restrict__ s3, u16* __restrict__ d3, int n3,
                           const float* __restrict__ s4, u16* __restrict__ d4, int n4,
                           const float* __restrict__ s5, u16* __restrict__ d5, int n5) {
  int total = n0 + n1 + n2 + n3 + n4 + n5;
  int stride = gridDim.x * 256;
  for (int i = blockIdx.x * 256 + threadIdx.x; i < total; i += stride) {
    const float* s; u16* d; int k = i;
    if (k < n0) { s = s0; d = d0; }
    else { k -= n0;
      if (k < n1) { s = s1; d = d1; }
      else { k -= n1;
        if (k < n2) { s = s2; d = d2; }
        else { k -= n2;
          if (k < n3) { s = s3; d = d3; }
          else { k -= n3;
            if (k < n4) { s = s4; d = d4; }
            else { k -= n4; s = s5; d = d5; }
          }
        }
      }
    }
    float4 a = ((const float4*)s)[2 * k];
    float4 b = ((const float4*)s)[2 * k + 1];
    s16x8 r;
    r[0] = (short)f2bf(a.x); r[1] = (short)f2bf(a.y);
    r[2] = (short)f2bf(a.z); r[3] = (short)f2bf(a.w);
    r[4] = (short)f2bf(b.x); r[5] = (short)f2bf(b.y);
    r[6] = (short)f2bf(b.z); r[7] = (short)f2bf(b.w);
    ((s16x8*)d)[k] = r;
  }
}

__global__ void k_zero(int* __restrict__ counts) {
  if (threadIdx.x < NEXP) counts[threadIdx.x] = 0;
}

// ---------------- router: 4 waves/token, 2 experts/wave, fused x->bf16 ----------------
__global__ void k_router(const float* __restrict__ x, const float* __restrict__ gw,
                         u16* __restrict__ xb,
                         float* __restrict__ tkw, int* __restrict__ tki,
                         int* __restrict__ counts) {
  __shared__ double sm[NEXP];
  int t = blockIdx.x;
  int tid = threadIdx.x;
  int lane = tid & 63, wv = tid >> 6;     // 4 waves
  const float4* xr = (const float4*)(x + (size_t)t * DMODEL);
  const float4* gr = (const float4*)gw;
  int e0 = wv * 2, e1 = e0 + 1;
  double a0 = 0.0, a1 = 0.0;
#pragma unroll
  for (int it = 0; it < DMODEL / 4 / 64; ++it) {   // 8 iters
    int idx = it * 64 + lane;
    float4 xv = xr[idx];
    float4 g0 = gr[e0 * (DMODEL / 4) + idx];
    float4 g1 = gr[e1 * (DMODEL / 4) + idx];
    a0 += (double)xv.x * g0.x + (double)xv.y * g0.y +
          (double)xv.z * g0.z + (double)xv.w * g0.w;
    a1 += (double)xv.x * g1.x + (double)xv.y * g1.y +
          (double)xv.z * g1.z + (double)xv.w * g1.w;
    if (wv == 0) {   // fused x -> bf16 (wave 0 only)
      u16x4 r = { f2bf(xv.x), f2bf(xv.y), f2bf(xv.z), f2bf(xv.w) };
      ((u16x4*)(xb + (size_t)t * DMODEL))[idx] = r;
    }
  }
#pragma unroll
  for (int off = 32; off; off >>= 1) {
    a0 += __shfl_down(a0, off, 64);
    a1 += __shfl_down(a1, off, 64);
  }
  if (lane == 0) { sm[e0] = a0; sm[e1] = a1; }
  __syncthreads();
  if (tid == 0) {
    double acc[NEXP];
#pragma unroll
    for (int e = 0; e < NEXP; ++e) acc[e] = sm[e];
    int i0 = 0; double v0 = acc[0];
    for (int e = 1; e < NEXP; ++e) if (acc[e] > v0) { v0 = acc[e]; i0 = e; }
    int i1 = -1; double v1 = -1e300;
    for (int e = 0; e < NEXP; ++e) if (e != i0 && acc[e] > v1) { v1 = acc[e]; i1 = e; }
    double r = exp(v1 - v0);
    float w0 = (float)(1.0 / (1.0 + r));
    float w1 = 1.0f - w0;
    tkw[2 * t] = w0; tkw[2 * t + 1] = w1;
    tki[2 * t] = i0; tki[2 * t + 1] = i1;
    atomicAdd(&counts[i0], 1);
    atomicAdd(&counts[i1], 1);
  }
}

// ---------------- merged scan + XCD-local schedule builder ----------------
// desc: bit31 = shared flag, bits24-27 = expert (0xF = sentinel), bits12-23 = mb,
// bits0-11 = nb. Each B-panel (one nb of one matrix) is assigned WHOLE to the
// least-loaded XCD; its m-blocks are emitted consecutively in that XCD's list.
// Table index = pos*8 + xcd, so blockIdx%8 == xcd under round-robin dispatch
// -> panel stays resident in that XCD's 4MB L2 across all its m-block re-reads.
// Shared panels assigned first (LPT for DN's 2x-K shared blocks).
__global__ void k_scan_sched(const int* __restrict__ counts, int* __restrict__ offs,
                             int* __restrict__ cursor, int* __restrict__ tblGU,
                             int* __restrict__ tblDN, int* __restrict__ nact) {
  if (threadIdx.x != 0 || blockIdx.x != 0) return;
  int s = 0;
  for (int e = 0; e < NEXP; ++e) { offs[e] = s; cursor[e] = s; s += counts[e]; }
  offs[NEXP] = s;
  for (int i = 0; i < GU_GRID; ++i) tblGU[i] = SENTINEL;
  for (int i = 0; i < DN_GRID; ++i) tblDN[i] = SENTINEL;

  int mb[NEXP];
  for (int e = 0; e < NEXP; ++e) mb[e] = (counts[e] + 255) >> 8;

  // ---- GU table
  {
    int load[8] = {0}, pos[8] = {0};
    // shared panels: nb 0..21, 16 m-blocks each
    for (int nb = 0; nb < DFFS / 128; ++nb) {
      int x = 0; for (int q = 1; q < 8; ++q) if (load[q] < load[x]) x = q;
      for (int m = 0; m < T_TOK / 256; ++m)
        tblGU[(pos[x]++) * 8 + x] = (int)(0x80000000u | (m << 12) | nb);
      load[x] += T_TOK / 256;
    }
    // routed panels: (e, nb 0..10), mb[e] m-blocks each
    for (int e = 0; e < NEXP; ++e)
      for (int nb = 0; nb < DFF / 128; ++nb) {
        if (mb[e] == 0) continue;
        int x = 0; for (int q = 1; q < 8; ++q) if (load[q] < load[x]) x = q;
        for (int m = 0; m < mb[e]; ++m)
          tblGU[(pos[x]++) * 8 + x] = (e << 24) | (m << 12) | nb;
        load[x] += mb[e];
      }
  }
  // ---- DN table (shared panel cost 2x: K=2816 vs 1408)
  {
    int load[8] = {0}, pos[8] = {0};
    for (int nb = 0; nb < DMODEL / 256; ++nb) {
      int x = 0; for (int q = 1; q < 8; ++q) if (load[q] < load[x]) x = q;
      for (int m = 0; m < T_TOK / 256; ++m)
        tblDN[(pos[x]++) * 8 + x] = (int)(0x80000000u | (m << 12) | nb);
      load[x] += 2 * (T_TOK / 256);
    }
    for (int e = 0; e < NEXP; ++e)
      for (int nb = 0; nb < DMODEL / 256; ++nb) {
        if (mb[e] == 0) continue;
        int x = 0; for (int q = 1; q < 8; ++q) if (load[q] < load[x]) x = q;
        for (int m = 0; m < mb[e]; ++m)
          tblDN[(pos[x]++) * 8 + x] = (e << 24) | (m << 12) | nb;
        load[x] += mb[e];
      }
  }
  nact[0] = GU_GRID; nact[1] = DN_GRID;
}

__global__ void k_assign(const int* __restrict__ tki, int* __restrict__ cursor,
                         int* __restrict__ pos, int* __restrict__ slot_tok) {
  int t = blockIdx.x * 256 + threadIdx.x;
  if (t >= T_TOK) return;
#pragma unroll
  for (int k = 0; k < 2; ++k) {
    int e = tki[2 * t + k];
    int p = atomicAdd(&cursor[e], 1);
    pos[2 * t + k] = p;
    slot_tok[p] = t;
  }
}

// ---------------- 256-row NT bf16 GEMM, reads-lead pipeline, fused-silu GU ----------
// PHASE 0 = gate/up+silu fused: 256m x 128 cols, B-tile rows interleaved
//   (wave wn's 64 B-rows = 32 wg-rows + 32 wu-rows of cols n0+wn*32..+31);
//   epilogue: h = silu(g)*u in-register, write h only.
// PHASE 1 = merged down (runtime K = 1408/2816), 256x256, writes yr / out.
// 512 thr = 8 waves (2M x 4N), BK=64, LDS 2 x 64KB dbuf, T2 XOR-swizzle.
template <int PHASE>
__launch_bounds__(512, 2)
__global__ void k_gemm8(const int* __restrict__ tbl, const int* __restrict__ nact,
                        const u16* __restrict__ xb,
                        const u16* __restrict__ hr, const u16* __restrict__ hs,
                        const u16* __restrict__ wbg, const u16* __restrict__ wbu,
                        const u16* __restrict__ wbd,
                        const u16* __restrict__ wbsg, const u16* __restrict__ wbsu,
                        const u16* __restrict__ wbsd,
                        u16* __restrict__ P1r, u16* __restrict__ P1s,
                        u16* __restrict__ yr, float* __restrict__ out,
                        const int* __restrict__ offs, const int* __restrict__ counts,
                        const int* __restrict__ slot_tok) {
  __shared__ __attribute__((aligned(16))) u16 lds[2 * 32768];  // 128 KiB

  const int desc = tbl[blockIdx.x];
  const int e = (desc >> 24) & 0xF;
  if (e == 0xF) return;                    // sentinel padding
  const bool shrd = desc < 0;
  const int m0 = ((desc >> 12) & 0xFFF) * 256;
  const int n0 = (desc & 0xFFF) * (PHASE == 0 ? 128 : 256);

  const u16 *A, *Bg, *Bu;
  u16* C1;
  float* OF = nullptr;
  int base, cnt, HS, K;
  bool gather = false;
  if constexpr (PHASE == 0) {
    K = DMODEL;
    if (shrd) {
      A = xb; base = 0; cnt = T_TOK;
      Bg = wbsg; Bu = wbsu; C1 = P1s; HS = DFFS;
    } else {
      A = xb; gather = true; base = offs[e]; cnt = counts[e];
      size_t es = (size_t)e * DFF * DMODEL;
      Bg = wbg + es; Bu = wbu + es; C1 = P1r; HS = DFF;
    }
  } else {
    HS = DMODEL;
    if (shrd) {
      A = hs; base = 0; cnt = T_TOK; K = DFFS;
      Bg = Bu = wbsd; OF = out; C1 = nullptr;
    } else {
      A = hr; base = offs[e]; cnt = counts[e]; K = DFF;
      Bg = Bu = wbd + (size_t)e * DMODEL * DFF; C1 = yr;
    }
  }
  if (m0 >= cnt) return;
  const int NT = K >> 6;

  int tid = threadIdx.x;
  int lane = tid & 63, wv = tid >> 6;
  int wm = wv >> 2, wn = wv & 3;
  int fr = lane & 15, fq = lane >> 4;

  // --- staging source pointers: 4 A-slabs + 4 B-slabs (64 rows each)
  int srow = tid >> 3;                     // wv*8 + (lane>>3), 0..63
  int sslot = (tid & 7) ^ (srow & 7);      // T2 pre-swizzle (involution)
  const u16* ap[4]; const u16* bp[4];
#pragma unroll
  for (int h = 0; h < 4; ++h) {
    int r = h * 64 + srow;                 // tile row 0..255
    int ra = m0 + r; ra = ra < cnt ? ra : cnt - 1;
    int ga = gather ? slot_tok[base + ra] : base + ra;
    ap[h] = A + (size_t)ga * K + sslot * 8;
    const u16* bb;
    if constexpr (PHASE == 0) {
      // interleaved g/u B-tile: row r -> wave wn_r = r>>6, s = r&63;
      // s<32: wg col n0+wn_r*32+s ; s>=32: wu col n0+wn_r*32+(s-32)
      int wnr = r >> 6, s = r & 63;
      int col = n0 + wnr * 32 + (s & 31);
      bb = (s < 32 ? Bg : Bu) + (size_t)col * K;
    } else {
      bb = Bg + (size_t)(n0 + r) * K;
    }
    bp[h] = bb + sslot * 8;
  }

#define STG_A(h, bufi, kt) gl16(ap[h] + (size_t)(kt) * 64, \
                                lds + (bufi) * 32768 + (h) * 4096 + wv * 512)
#define STG_B(h, bufi, kt) gl16(bp[h] + (size_t)(kt) * 64, \
                                lds + (bufi) * 32768 + 16384 + (h) * 4096 + wv * 512)

  // --- read bases (u16 units); swizzled k-slot is lane-constant per ks
  int sKs0 = ((0 + fq) ^ (fr & 7)) * 8;
  int sKs1 = ((4 + fq) ^ (fr & 7)) * 8;
  int aBase = wm * 8192 + fr * 64;                                   // + i*1024
  int bBase = 16384 + (wn >> 1) * 8192 + ((wn & 1) * 64 + fr) * 64;  // + j*1024

  f32x4 acc[8][4];
#pragma unroll
  for (int i = 0; i < 8; ++i)
#pragma unroll
    for (int j = 0; j < 4; ++j) acc[i][j] = (f32x4){0.f, 0.f, 0.f, 0.f};

  // prologue: full tile0 + A-slabs of tile1
  STG_A(0, 0, 0); STG_A(1, 0, 0); STG_A(2, 0, 0); STG_A(3, 0, 0);
  STG_B(0, 0, 0); STG_B(1, 0, 0); STG_B(2, 0, 0); STG_B(3, 0, 0);
  if (NT > 1) { STG_A(0, 1, 1); STG_A(1, 1, 1); STG_A(2, 1, 1); STG_A(3, 1, 1); }
  if (NT > 1) asm volatile("s_waitcnt vmcnt(4)" ::: "memory");
  else        asm volatile("s_waitcnt vmcnt(0)" ::: "memory");
  BARRIER();
  SBAR();

  bf16x8 rAa[4][2], rAb[4][2], rB01[2][2], rB23[2][2];
#pragma unroll
  for (int il = 0; il < 4; ++il) {
    rAa[il][0] = *(const bf16x8*)(lds + aBase + il * 1024 + sKs0);
    rAa[il][1] = *(const bf16x8*)(lds + aBase + il * 1024 + sKs1);
  }
#pragma unroll
  for (int jl = 0; jl < 2; ++jl) {
    rB01[jl][0] = *(const bf16x8*)(lds + bBase + jl * 1024 + sKs0);
    rB01[jl][1] = *(const bf16x8*)(lds + bBase + jl * 1024 + sKs1);
  }

  for (int t = 0; t < NT; ++t) {
    const int buf = t & 1, nbuf = buf ^ 1;
    const u16* lbuf = lds + buf * 32768;
    const u16* lbufN = lds + nbuf * 32768;
    const bool hn1 = (t + 1) < NT, hn2 = (t + 2) < NT;

    // ---- s0: read B23(t); stage B0,B1(t+1)->nbuf; MFMA mq0 x nq0
#pragma unroll
    for (int jl = 0; jl < 2; ++jl) {
      rB23[jl][0] = *(const bf16x8*)(lbuf + bBase + (2 + jl) * 1024 + sKs0);
      rB23[jl][1] = *(const bf16x8*)(lbuf + bBase + (2 + jl) * 1024 + sKs1);
    }
    if (hn1) { STG_B(0, nbuf, t + 1); STG_B(1, nbuf, t + 1); }
    __builtin_amdgcn_s_setprio(1);
#pragma unroll
    for (int il = 0; il < 4; ++il)
#pragma unroll
      for (int jl = 0; jl < 2; ++jl) {
        acc[il][jl] = __builtin_amdgcn_mfma_f32_16x16x32_bf16(rAa[il][0], rB01[jl][0], acc[il][jl], 0, 0, 0);
        acc[il][jl] = __builtin_amdgcn_mfma_f32_16x16x32_bf16(rAa[il][1], rB01[jl][1], acc[il][jl], 0, 0, 0);
      }
    __builtin_amdgcn_s_setprio(0);

    // ---- s1: read A13(t); stage B2,B3(t+1)->nbuf; MFMA mq0 x nq1
#pragma unroll
    for (int il = 0; il < 4; ++il) {
      rAb[il][0] = *(const bf16x8*)(lbuf + aBase + (4 + il) * 1024 + sKs0);
      rAb[il][1] = *(const bf16x8*)(lbuf + aBase + (4 + il) * 1024 + sKs1);
    }
    if (hn1) { STG_B(2, nbuf, t + 1); STG_B(3, nbuf, t + 1); }
    __builtin_amdgcn_s_setprio(1);
#pragma unroll
    for (int il = 0; il < 4; ++il)
#pragma unroll
      for (int jl = 0; jl < 2; ++jl) {
        acc[il][2 + jl] = __builtin_amdgcn_mfma_f32_16x16x32_bf16(rAa[il][0], rB23[jl][0], acc[il][2 + jl], 0, 0, 0);
        acc[il][2 + jl] = __builtin_amdgcn_mfma_f32_16x16x32_bf16(rAa[il][1], rB23[jl][1], acc[il][2 + jl], 0, 0, 0);
      }
    __builtin_amdgcn_s_setprio(0);

    // ---- s2: drain reads + barrier (frees buf for t+2 A-stages); MFMA mq1 x nq0
    asm volatile("s_waitcnt lgkmcnt(0)" ::: "memory");
    BARRIER();
    SBAR();
    if (hn2) { STG_A(0, buf, t + 2); STG_A(1, buf, t + 2); }
    __builtin_amdgcn_s_setprio(1);
#pragma unroll
    for (int il = 0; il < 4; ++il)
#pragma unroll
      for (int jl = 0; jl < 2; ++jl) {
        acc[4 + il][jl] = __builtin_amdgcn_mfma_f32_16x16x32_bf16(rAb[il][0], rB01[jl][0], acc[4 + il][jl], 0, 0, 0);
        acc[4 + il][jl] = __builtin_amdgcn_mfma_f32_16x16x32_bf16(rAb[il][1], rB01[jl][1], acc[4 + il][jl], 0, 0, 0);
      }
    __builtin_amdgcn_s_setprio(0);

    // ---- s3: vmcnt+barrier (t+1 fully staged); stage A2,A3(t+2); read A02/B01(t+1); MFMA mq1 x nq1
    if (hn1) {
      if (hn2) asm volatile("s_waitcnt vmcnt(2)" ::: "memory");
      else     asm volatile("s_waitcnt vmcnt(0)" ::: "memory");
      BARRIER();
      SBAR();
      if (hn2) { STG_A(2, buf, t + 2); STG_A(3, buf, t + 2); }
#pragma unroll
      for (int il = 0; il < 4; ++il) {
        rAa[il][0] = *(const bf16x8*)(lbufN + aBase + il * 1024 + sKs0);
        rAa[il][1] = *(const bf16x8*)(lbufN + aBase + il * 1024 + sKs1);
      }
#pragma unroll
      for (int jl = 0; jl < 2; ++jl) {
        rB01[jl][0] = *(const bf16x8*)(lbufN + bBase + jl * 1024 + sKs0);
        rB01[jl][1] = *(const bf16x8*)(lbufN + bBase + jl * 1024 + sKs1);
      }
    }
    __builtin_amdgcn_s_setprio(1);
#pragma unroll
    for (int il = 0; il < 4; ++il)
#pragma unroll
      for (int jl = 0; jl < 2; ++jl) {
        acc[4 + il][2 + jl] = __builtin_amdgcn_mfma_f32_16x16x32_bf16(rAb[il][0], rB23[jl][0], acc[4 + il][2 + jl], 0, 0, 0);
        acc[4 + il][2 + jl] = __builtin_amdgcn_mfma_f32_16x16x32_bf16(rAb[il][1], rB23[jl][1], acc[4 + il][2 + jl], 0, 0, 0);
      }
    __builtin_amdgcn_s_setprio(0);
  }
#undef STG_A
#undef STG_B

  // --- epilogue ---
#pragma unroll
  for (int i = 0; i < 8; ++i) {
    int row_t = wm * 128 + i * 16 + fq * 4;
#pragma unroll
    for (int r = 0; r < 4; ++r) {
      int m = m0 + row_t + r;
      if (m >= cnt) continue;
      size_t rowoff = (size_t)(base + m) * (size_t)HS;
      if constexpr (PHASE == 0) {
        // h = silu(g) * u ; g = acc[i][jl], u = acc[i][2+jl], col = n0+wn*32+jl*16+fr
#pragma unroll
        for (int jl = 0; jl < 2; ++jl) {
          float g = acc[i][jl][r];
          float u = acc[i][2 + jl][r];
          float hval = (g / (1.f + __expf(-g))) * u;
          C1[rowoff + (n0 + wn * 32 + jl * 16 + fr)] = f2bf(hval);
        }
      } else {
#pragma unroll
        for (int j = 0; j < 4; ++j) {
          int col_t = n0 + wn * 64 + j * 16 + fr;
          float v = acc[i][j][r];
          if (shrd) OF[rowoff + col_t] = v;
          else      C1[rowoff + col_t] = f2bf(v);
        }
      }
    }
  }
}

// ---------------- y[t] += w0*yr[pos0] + w1*yr[pos1] ----------------
__global__ void k_combine(float* __restrict__ y, const u16* __restrict__ yr,
                          const float* __restrict__ tkw, const int* __restrict__ pos) {
  int t = blockIdx.x;
  int i = threadIdx.x;
  float w0 = tkw[2 * t], w1 = tkw[2 * t + 1];
  size_t p0 = (size_t)pos[2 * t] * DMODEL, p1 = (size_t)pos[2 * t + 1] * DMODEL;
  int d0 = i * 8;
  s16x8 a = *(const s16x8*)(yr + p0 + d0);
  s16x8 b = *(const s16x8*)(yr + p1 + d0);
  float* yo = y + (size_t)t * DMODEL + d0;
#pragma unroll
  for (int j = 0; j < 8; ++j)
    yo[j] += w0 * bf2f((u16)a[j]) + w1 * bf2f((u16)b[j]);
}

extern "C" void kernel_launch(void* const* d_in, const int* in_sizes, int n_in,
                              void* d_out, int out_size, void* d_ws, size_t ws_size,
                              hipStream_t stream) {
  const float* x   = (const float*)d_in[0];
  const float* gw  = (const float*)d_in[1];
  const float* wg  = (const float*)d_in[2];
  const float* wu  = (const float*)d_in[3];
  const float* wd  = (const float*)d_in[4];
  const float* wsg = (const float*)d_in[5];
  const float* wsu = (const float*)d_in[6];
  const float* wsd = (const float*)d_in[7];
  float* out = (float*)d_out;

  char* ws = (char*)d_ws;
  size_t o = 0;
  auto alloc = [&](size_t bytes) -> void* {
    void* p = ws + o;
    o += (bytes + 255) & ~(size_t)255;
    return p;
  };
  u16* xb   = (u16*)alloc((size_t)T_TOK * DMODEL * 2);
  u16* wbg  = (u16*)alloc((size_t)NEXP * DFF * DMODEL * 2);
  u16* wbu  = (u16*)alloc((size_t)NEXP * DFF * DMODEL * 2);
  u16* wbd  = (u16*)alloc((size_t)NEXP * DMODEL * DFF * 2);
  u16* wbsg = (u16*)alloc((size_t)DFFS * DMODEL * 2);
  u16* wbsu = (u16*)alloc((size_t)DFFS * DMODEL * 2);
  u16* wbsd = (u16*)alloc((size_t)DMODEL * DFFS * 2);
  u16* P1r  = (u16*)alloc((size_t)NSLOT * DFF * 2);    // h_r (silu fused in GU)
  u16* P1s  = (u16*)alloc((size_t)T_TOK * DFFS * 2);   // h_s
  u16* yr   = (u16*)alloc((size_t)NSLOT * DMODEL * 2);
  float* tkw = (float*)alloc((size_t)T_TOK * 2 * 4);
  int* tki   = (int*)alloc((size_t)T_TOK * 2 * 4);
  int* pos   = (int*)alloc((size_t)T_TOK * 2 * 4);
  int* slot_tok = (int*)alloc((size_t)NSLOT * 4);
  int* counts   = (int*)alloc(64);
  int* offs     = (int*)alloc(64);
  int* cursor   = (int*)alloc(64);
  int* tblGU    = (int*)alloc(GU_GRID * 4);
  int* tblDN    = (int*)alloc(DN_GRID * 4);
  int* nact     = (int*)alloc(64);
  if (o > ws_size) {
    fprintf(stderr, "kernel_launch: ws too small: need %zu have %zu\n", o, ws_size);
    return;
  }

  // --- merged weight conversion (single dispatch, grid-stride) ---
  {
    int n8w = NEXP * DFF * DMODEL / 8;
    int n8s = DFFS * DMODEL / 8;
    k_convert6<<<2048, 256, 0, stream>>>(wg, wbg, n8w, wu, wbu, n8w, wd, wbd, n8w,
                                         wsg, wbsg, n8s, wsu, wbsu, n8s, wsd, wbsd, n8s);
  }

  // --- routing (also produces xb) + schedule tables ---
  k_zero<<<1, 64, 0, stream>>>(counts);
  k_router<<<T_TOK, 256, 0, stream>>>(x, gw, xb, tkw, tki, counts);
  k_scan_sched<<<1, 64, 0, stream>>>(counts, offs, cursor, tblGU, tblDN, nact);
  k_assign<<<(T_TOK + 255) / 256, 256, 0, stream>>>(tki, cursor, pos, slot_tok);

  // --- merged gate/up GEMM with fused silu (routed + shared) ---
  k_gemm8<0><<<GU_GRID, 512, 0, stream>>>(
      tblGU, nact, xb, nullptr, nullptr,
      wbg, wbu, wbd, wbsg, wbsu, wbsd,
      P1r, P1s, yr, out, offs, counts, slot_tok);

  // --- merged down GEMM (routed -> yr, shared -> out) ---
  k_gemm8<1><<<DN_GRID, 512, 0, stream>>>(
      tblDN, nact, xb, P1r, P1s,
      wbg, wbu, wbd, wbsg, wbsu, wbsd,
      P1r, P1s, yr, out, offs, counts, slot_tok);

  // --- combine routed into output ---
  k_combine<<<T_TOK, 256, 0, stream>>>(out, yr, tkw, pos);
}

// Round 11
// 565.709 us; speedup vs baseline: 1.1449x; 1.1449x over previous
//
#include <hip/hip_runtime.h>
#include <stdint.h>
#include <stdio.h>

#define T_TOK 4096
#define DMODEL 2048
#define NEXP 8
#define DFF 1408
#define DFFS 2816
#define NSLOT 8192   // T_TOK * 2

// schedule-table grid bounds (worst case): routed m-blocks sum <= 39
#define GU_GRID (16 * 22 + 39 * 11)   // 781
#define DN_GRID (16 * 8 + 39 * 8)     // 440

typedef unsigned short u16;
typedef short s16x8 __attribute__((ext_vector_type(8)));
typedef unsigned short u16x4 __attribute__((ext_vector_type(4)));
typedef __bf16 bf16x8 __attribute__((ext_vector_type(8)));
typedef float f32x4 __attribute__((ext_vector_type(4)));

__device__ __forceinline__ u16 f2bf(float f) {
  uint32_t u = __builtin_bit_cast(uint32_t, f);
  u += 0x7fffu + ((u >> 16) & 1u);
  return (u16)(u >> 16);
}
__device__ __forceinline__ float bf2f(u16 h) {
  uint32_t u = ((uint32_t)h) << 16;
  return __builtin_bit_cast(float, u);
}

// async global->LDS, 16B per lane; LDS dest = wave-uniform base + lane*16
__device__ __forceinline__ void gl16(const u16* g, u16* l) {
  __builtin_amdgcn_global_load_lds((const __attribute__((address_space(1))) void*)g,
                                   (__attribute__((address_space(3))) void*)l,
                                   16, 0, 0);
}

#define BARRIER() asm volatile("s_barrier" ::: "memory")
#define SBAR()    __builtin_amdgcn_sched_barrier(0)

// ---------------- merged fp32 -> bf16 convert (grid-stride, 8 elems/iter) ----------------
__global__ void k_convert6(const float* __restrict__ s0, u16* __restrict__ d0, int n0,
                           const float* __restrict__ s1, u16* __restrict__ d1, int n1,
                           const float* __restrict__ s2, u16* __restrict__ d2, int n2,
                           const float* __restrict__ s3, u16* __restrict__ d3, int n3,
                           const float* __restrict__ s4, u16* __restrict__ d4, int n4,
                           const float* __restrict__ s5, u16* __restrict__ d5, int n5) {
  int total = n0 + n1 + n2 + n3 + n4 + n5;
  int stride = gridDim.x * 256;
  for (int i = blockIdx.x * 256 + threadIdx.x; i < total; i += stride) {
    const float* s; u16* d; int k = i;
    if (k < n0) { s = s0; d = d0; }
    else { k -= n0;
      if (k < n1) { s = s1; d = d1; }
      else { k -= n1;
        if (k < n2) { s = s2; d = d2; }
        else { k -= n2;
          if (k < n3) { s = s3; d = d3; }
          else { k -= n3;
            if (k < n4) { s = s4; d = d4; }
            else { k -= n4; s = s5; d = d5; }
          }
        }
      }
    }
    float4 a = ((const float4*)s)[2 * k];
    float4 b = ((const float4*)s)[2 * k + 1];
    s16x8 r;
    r[0] = (short)f2bf(a.x); r[1] = (short)f2bf(a.y);
    r[2] = (short)f2bf(a.z); r[3] = (short)f2bf(a.w);
    r[4] = (short)f2bf(b.x); r[5] = (short)f2bf(b.y);
    r[6] = (short)f2bf(b.z); r[7] = (short)f2bf(b.w);
    ((s16x8*)d)[k] = r;
  }
}

__global__ void k_zero(int* __restrict__ counts) {
  if (threadIdx.x < NEXP) counts[threadIdx.x] = 0;
}

// ---------------- router: 4 waves/token, 2 experts/wave, fused x->bf16 ----------------
__global__ void k_router(const float* __restrict__ x, const float* __restrict__ gw,
                         u16* __restrict__ xb,
                         float* __restrict__ tkw, int* __restrict__ tki,
                         int* __restrict__ counts) {
  __shared__ double sm[NEXP];
  int t = blockIdx.x;
  int tid = threadIdx.x;
  int lane = tid & 63, wv = tid >> 6;     // 4 waves
  const float4* xr = (const float4*)(x + (size_t)t * DMODEL);
  const float4* gr = (const float4*)gw;
  int e0 = wv * 2, e1 = e0 + 1;
  double a0 = 0.0, a1 = 0.0;
#pragma unroll
  for (int it = 0; it < DMODEL / 4 / 64; ++it) {   // 8 iters
    int idx = it * 64 + lane;
    float4 xv = xr[idx];
    float4 g0 = gr[e0 * (DMODEL / 4) + idx];
    float4 g1 = gr[e1 * (DMODEL / 4) + idx];
    a0 += (double)xv.x * g0.x + (double)xv.y * g0.y +
          (double)xv.z * g0.z + (double)xv.w * g0.w;
    a1 += (double)xv.x * g1.x + (double)xv.y * g1.y +
          (double)xv.z * g1.z + (double)xv.w * g1.w;
    if (wv == 0) {   // fused x -> bf16 (wave 0 only)
      u16x4 r = { f2bf(xv.x), f2bf(xv.y), f2bf(xv.z), f2bf(xv.w) };
      ((u16x4*)(xb + (size_t)t * DMODEL))[idx] = r;
    }
  }
#pragma unroll
  for (int off = 32; off; off >>= 1) {
    a0 += __shfl_down(a0, off, 64);
    a1 += __shfl_down(a1, off, 64);
  }
  if (lane == 0) { sm[e0] = a0; sm[e1] = a1; }
  __syncthreads();
  if (tid == 0) {
    double acc[NEXP];
#pragma unroll
    for (int e = 0; e < NEXP; ++e) acc[e] = sm[e];
    int i0 = 0; double v0 = acc[0];
    for (int e = 1; e < NEXP; ++e) if (acc[e] > v0) { v0 = acc[e]; i0 = e; }
    int i1 = -1; double v1 = -1e300;
    for (int e = 0; e < NEXP; ++e) if (e != i0 && acc[e] > v1) { v1 = acc[e]; i1 = e; }
    double r = exp(v1 - v0);
    float w0 = (float)(1.0 / (1.0 + r));
    float w1 = 1.0f - w0;
    tkw[2 * t] = w0; tkw[2 * t + 1] = w1;
    tki[2 * t] = i0; tki[2 * t + 1] = i1;
    atomicAdd(&counts[i0], 1);
    atomicAdd(&counts[i1], 1);
  }
}

// ---------------- merged scan + schedule-table builder (round-9 ordering) ----------------
// desc: bit31 = shared flag, bits24-27 = expert, bits12-23 = mb, bits0-11 = nb.
// GU: nb indexes 128-col panels (g+u fused per block). DN: nb indexes 256-col.
// Shared entries FIRST (LPT for DOWN: shared-down blocks have 2x the K).
__global__ void k_scan_sched(const int* __restrict__ counts, int* __restrict__ offs,
                             int* __restrict__ cursor, int* __restrict__ tblGU,
                             int* __restrict__ tblDN, int* __restrict__ nact) {
  if (threadIdx.x != 0 || blockIdx.x != 0) return;
  int s = 0;
  for (int e = 0; e < NEXP; ++e) { offs[e] = s; cursor[e] = s; s += counts[e]; }
  offs[NEXP] = s;
  int g = 0, d = 0;
  for (int m = 0; m < T_TOK / 256; ++m) {
    for (int nb = 0; nb < DFFS / 128; ++nb)
      tblGU[g++] = (int)(0x80000000u | (m << 12) | nb);
    for (int nb = 0; nb < DMODEL / 256; ++nb)
      tblDN[d++] = (int)(0x80000000u | (m << 12) | nb);
  }
  for (int e = 0; e < NEXP; ++e) {
    int mb = (counts[e] + 255) >> 8;
    for (int m = 0; m < mb; ++m) {
      for (int nb = 0; nb < DFF / 128; ++nb)
        tblGU[g++] = (e << 24) | (m << 12) | nb;
      for (int nb = 0; nb < DMODEL / 256; ++nb)
        tblDN[d++] = (e << 24) | (m << 12) | nb;
    }
  }
  nact[0] = g; nact[1] = d;
}

__global__ void k_assign(const int* __restrict__ tki, int* __restrict__ cursor,
                         int* __restrict__ pos, int* __restrict__ slot_tok) {
  int t = blockIdx.x * 256 + threadIdx.x;
  if (t >= T_TOK) return;
#pragma unroll
  for (int k = 0; k < 2; ++k) {
    int e = tki[2 * t + k];
    int p = atomicAdd(&cursor[e], 1);
    pos[2 * t + k] = p;
    slot_tok[p] = t;
  }
}

// ---------------- 256-row NT bf16 GEMM, deep-lead 4-phase pipeline, fused-silu GU ----
// PHASE 0 = gate/up+silu fused: 256m x 128 cols, B-tile rows interleaved;
//   epilogue computes h = silu(g)*u in-register, writes h only.
// PHASE 1 = merged down (runtime K = 1408/2816), 256x256, writes yr / out.
// 512 thr = 8 waves (2M x 4N), BK=64, LDS 2 x 64KB dbuf, T2 XOR-swizzle.
// Ledger (new this round): ALL 8 staging calls for tile t+2 issue at s2 (after
// lgkm(0)+barrier proves buf's reads are done). s3 waits vmcnt(8): batch(t+1)
// was issued at (t-1).s2 -> 5 phases (~2.7k cy) of lead for A AND B.
//   s0: read rB23(t);                MFMA q00 (rAa x rB01)
//   s1: read rAb(t);                 MFMA q01 (rAa x rB23)
//   s2: lgkm(0); BAR; stage8(t+2)->buf;  MFMA q10 (rAb x rB01)
//   s3: vmcnt(8|0); BAR; read rAa,rB01(t+1) from nbuf;  MFMA q11 (rAb x rB23)
template <int PHASE>
__launch_bounds__(512, 2)
__global__ void k_gemm8(const int* __restrict__ tbl, const int* __restrict__ nact,
                        const u16* __restrict__ xb,
                        const u16* __restrict__ hr, const u16* __restrict__ hs,
                        const u16* __restrict__ wbg, const u16* __restrict__ wbu,
                        const u16* __restrict__ wbd,
                        const u16* __restrict__ wbsg, const u16* __restrict__ wbsu,
                        const u16* __restrict__ wbsd,
                        u16* __restrict__ P1r, u16* __restrict__ P1s,
                        u16* __restrict__ yr, float* __restrict__ out,
                        const int* __restrict__ offs, const int* __restrict__ counts,
                        const int* __restrict__ slot_tok) {
  __shared__ __attribute__((aligned(16))) u16 lds[2 * 32768];  // 128 KiB

  if ((int)blockIdx.x >= nact[PHASE]) return;
  const int desc = tbl[blockIdx.x];
  const bool shrd = desc < 0;
  const int e = (desc >> 24) & 0xF;
  const int m0 = ((desc >> 12) & 0xFFF) * 256;
  const int n0 = (desc & 0xFFF) * (PHASE == 0 ? 128 : 256);

  const u16 *A, *Bg, *Bu;
  u16* C1;
  float* OF = nullptr;
  int base, cnt, HS, K;
  bool gather = false;
  if constexpr (PHASE == 0) {
    K = DMODEL;
    if (shrd) {
      A = xb; base = 0; cnt = T_TOK;
      Bg = wbsg; Bu = wbsu; C1 = P1s; HS = DFFS;
    } else {
      A = xb; gather = true; base = offs[e]; cnt = counts[e];
      size_t es = (size_t)e * DFF * DMODEL;
      Bg = wbg + es; Bu = wbu + es; C1 = P1r; HS = DFF;
    }
  } else {
    HS = DMODEL;
    if (shrd) {
      A = hs; base = 0; cnt = T_TOK; K = DFFS;
      Bg = Bu = wbsd; OF = out; C1 = nullptr;
    } else {
      A = hr; base = offs[e]; cnt = counts[e]; K = DFF;
      Bg = Bu = wbd + (size_t)e * DMODEL * DFF; C1 = yr;
    }
  }
  const int NT = K >> 6;

  int tid = threadIdx.x;
  int lane = tid & 63, wv = tid >> 6;
  int wm = wv >> 2, wn = wv & 3;
  int fr = lane & 15, fq = lane >> 4;

  // --- staging source pointers: 4 A-slabs + 4 B-slabs (64 rows each)
  int srow = tid >> 3;                     // wv*8 + (lane>>3), 0..63
  int sslot = (tid & 7) ^ (srow & 7);      // T2 pre-swizzle (involution)
  const u16* ap[4]; const u16* bp[4];
#pragma unroll
  for (int h = 0; h < 4; ++h) {
    int r = h * 64 + srow;                 // tile row 0..255
    int ra = m0 + r; ra = ra < cnt ? ra : cnt - 1;
    int ga = gather ? slot_tok[base + ra] : base + ra;
    ap[h] = A + (size_t)ga * K + sslot * 8;
    const u16* bb;
    if constexpr (PHASE == 0) {
      // interleaved g/u B-tile: row r -> wave wn_r = r>>6, s = r&63;
      // s<32: wg col n0+wn_r*32+s ; s>=32: wu col n0+wn_r*32+(s-32)
      int wnr = r >> 6, s = r & 63;
      int col = n0 + wnr * 32 + (s & 31);
      bb = (s < 32 ? Bg : Bu) + (size_t)col * K;
    } else {
      bb = Bg + (size_t)(n0 + r) * K;
    }
    bp[h] = bb + sslot * 8;
  }

#define STG_A(h, bufi, kt) gl16(ap[h] + (size_t)(kt) * 64, \
                                lds + (bufi) * 32768 + (h) * 4096 + wv * 512)
#define STG_B(h, bufi, kt) gl16(bp[h] + (size_t)(kt) * 64, \
                                lds + (bufi) * 32768 + 16384 + (h) * 4096 + wv * 512)
#define STG8(bufi, kt) { STG_A(0, bufi, kt); STG_A(1, bufi, kt); \
                         STG_A(2, bufi, kt); STG_A(3, bufi, kt); \
                         STG_B(0, bufi, kt); STG_B(1, bufi, kt); \
                         STG_B(2, bufi, kt); STG_B(3, bufi, kt); }

  // --- read bases (u16 units); swizzled k-slot is lane-constant per ks
  int sKs0 = ((0 + fq) ^ (fr & 7)) * 8;
  int sKs1 = ((4 + fq) ^ (fr & 7)) * 8;
  int aBase = wm * 8192 + fr * 64;                                   // + i*1024
  int bBase = 16384 + (wn >> 1) * 8192 + ((wn & 1) * 64 + fr) * 64;  // + j*1024

  f32x4 acc[8][4];
#pragma unroll
  for (int i = 0; i < 8; ++i)
#pragma unroll
    for (int j = 0; j < 4; ++j) acc[i][j] = (f32x4){0.f, 0.f, 0.f, 0.f};

  // prologue: stage tile0 -> buf0 and tile1 -> buf1 (16 calls), wait tile0 only
  STG8(0, 0);
  if (NT > 1) { STG8(1, 1); asm volatile("s_waitcnt vmcnt(8)" ::: "memory"); }
  else        {             asm volatile("s_waitcnt vmcnt(0)" ::: "memory"); }
  BARRIER();
  SBAR();

  bf16x8 rAa[4][2], rAb[4][2], rB01[2][2], rB23[2][2];
#pragma unroll
  for (int il = 0; il < 4; ++il) {
    rAa[il][0] = *(const bf16x8*)(lds + aBase + il * 1024 + sKs0);
    rAa[il][1] = *(const bf16x8*)(lds + aBase + il * 1024 + sKs1);
  }
#pragma unroll
  for (int jl = 0; jl < 2; ++jl) {
    rB01[jl][0] = *(const bf16x8*)(lds + bBase + jl * 1024 + sKs0);
    rB01[jl][1] = *(const bf16x8*)(lds + bBase + jl * 1024 + sKs1);
  }

  for (int t = 0; t < NT; ++t) {
    const int buf = t & 1, nbuf = buf ^ 1;
    const u16* lbuf = lds + buf * 32768;
    const u16* lbufN = lds + nbuf * 32768;
    const bool hn1 = (t + 1) < NT, hn2 = (t + 2) < NT;

    // ---- s0: read rB23(t); MFMA q00
#pragma unroll
    for (int jl = 0; jl < 2; ++jl) {
      rB23[jl][0] = *(const bf16x8*)(lbuf + bBase + (2 + jl) * 1024 + sKs0);
      rB23[jl][1] = *(const bf16x8*)(lbuf + bBase + (2 + jl) * 1024 + sKs1);
    }
    __builtin_amdgcn_s_setprio(1);
#pragma unroll
    for (int il = 0; il < 4; ++il)
#pragma unroll
      for (int jl = 0; jl < 2; ++jl) {
        acc[il][jl] = __builtin_amdgcn_mfma_f32_16x16x32_bf16(rAa[il][0], rB01[jl][0], acc[il][jl], 0, 0, 0);
        acc[il][jl] = __builtin_amdgcn_mfma_f32_16x16x32_bf16(rAa[il][1], rB01[jl][1], acc[il][jl], 0, 0, 0);
      }
    __builtin_amdgcn_s_setprio(0);

    // ---- s1: read rAb(t); MFMA q01
#pragma unroll
    for (int il = 0; il < 4; ++il) {
      rAb[il][0] = *(const bf16x8*)(lbuf + aBase + (4 + il) * 1024 + sKs0);
      rAb[il][1] = *(const bf16x8*)(lbuf + aBase + (4 + il) * 1024 + sKs1);
    }
    __builtin_amdgcn_s_setprio(1);
#pragma unroll
    for (int il = 0; il < 4; ++il)
#pragma unroll
      for (int jl = 0; jl < 2; ++jl) {
        acc[il][2 + jl] = __builtin_amdgcn_mfma_f32_16x16x32_bf16(rAa[il][0], rB23[jl][0], acc[il][2 + jl], 0, 0, 0);
        acc[il][2 + jl] = __builtin_amdgcn_mfma_f32_16x16x32_bf16(rAa[il][1], rB23[jl][1], acc[il][2 + jl], 0, 0, 0);
      }
    __builtin_amdgcn_s_setprio(0);

    // ---- s2: lgkm(0)+barrier (buf reads done); stage8(t+2)->buf; MFMA q10
    asm volatile("s_waitcnt lgkmcnt(0)" ::: "memory");
    BARRIER();
    SBAR();
    if (hn2) STG8(buf, t + 2);
    __builtin_amdgcn_s_setprio(1);
#pragma unroll
    for (int il = 0; il < 4; ++il)
#pragma unroll
      for (int jl = 0; jl < 2; ++jl) {
        acc[4 + il][jl] = __builtin_amdgcn_mfma_f32_16x16x32_bf16(rAb[il][0], rB01[jl][0], acc[4 + il][jl], 0, 0, 0);
        acc[4 + il][jl] = __builtin_amdgcn_mfma_f32_16x16x32_bf16(rAb[il][1], rB01[jl][1], acc[4 + il][jl], 0, 0, 0);
      }
    __builtin_amdgcn_s_setprio(0);

    // ---- s3: vmcnt(8|0)+barrier (t+1 resident, 5-phase lead); read rAa/rB01(t+1); MFMA q11
    if (hn1) {
      if (hn2) asm volatile("s_waitcnt vmcnt(8)" ::: "memory");
      else     asm volatile("s_waitcnt vmcnt(0)" ::: "memory");
      BARRIER();
      SBAR();
#pragma unroll
      for (int il = 0; il < 4; ++il) {
        rAa[il][0] = *(const bf16x8*)(lbufN + aBase + il * 1024 + sKs0);
        rAa[il][1] = *(const bf16x8*)(lbufN + aBase + il * 1024 + sKs1);
      }
#pragma unroll
      for (int jl = 0; jl < 2; ++jl) {
        rB01[jl][0] = *(const bf16x8*)(lbufN + bBase + jl * 1024 + sKs0);
        rB01[jl][1] = *(const bf16x8*)(lbufN + bBase + jl * 1024 + sKs1);
      }
    }
    __builtin_amdgcn_s_setprio(1);
#pragma unroll
    for (int il = 0; il < 4; ++il)
#pragma unroll
      for (int jl = 0; jl < 2; ++jl) {
        acc[4 + il][2 + jl] = __builtin_amdgcn_mfma_f32_16x16x32_bf16(rAb[il][0], rB23[jl][0], acc[4 + il][2 + jl], 0, 0, 0);
        acc[4 + il][2 + jl] = __builtin_amdgcn_mfma_f32_16x16x32_bf16(rAb[il][1], rB23[jl][1], acc[4 + il][2 + jl], 0, 0, 0);
      }
    __builtin_amdgcn_s_setprio(0);
  }
#undef STG_A
#undef STG_B
#undef STG8

  // --- epilogue ---
#pragma unroll
  for (int i = 0; i < 8; ++i) {
    int row_t = wm * 128 + i * 16 + fq * 4;
#pragma unroll
    for (int r = 0; r < 4; ++r) {
      int m = m0 + row_t + r;
      if (m >= cnt) continue;
      size_t rowoff = (size_t)(base + m) * (size_t)HS;
      if constexpr (PHASE == 0) {
        // h = silu(g) * u ; g = acc[i][jl], u = acc[i][2+jl], col = n0+wn*32+jl*16+fr
#pragma unroll
        for (int jl = 0; jl < 2; ++jl) {
          float g = acc[i][jl][r];
          float u = acc[i][2 + jl][r];
          float hval = (g / (1.f + __expf(-g))) * u;
          C1[rowoff + (n0 + wn * 32 + jl * 16 + fr)] = f2bf(hval);
        }
      } else {
#pragma unroll
        for (int j = 0; j < 4; ++j) {
          int col_t = n0 + wn * 64 + j * 16 + fr;
          float v = acc[i][j][r];
          if (shrd) OF[rowoff + col_t] = v;
          else      C1[rowoff + col_t] = f2bf(v);
        }
      }
    }
  }
}

// ---------------- y[t] += w0*yr[pos0] + w1*yr[pos1] ----------------
__global__ void k_combine(float* __restrict__ y, const u16* __restrict__ yr,
                          const float* __restrict__ tkw, const int* __restrict__ pos) {
  int t = blockIdx.x;
  int i = threadIdx.x;
  float w0 = tkw[2 * t], w1 = tkw[2 * t + 1];
  size_t p0 = (size_t)pos[2 * t] * DMODEL, p1 = (size_t)pos[2 * t + 1] * DMODEL;
  int d0 = i * 8;
  s16x8 a = *(const s16x8*)(yr + p0 + d0);
  s16x8 b = *(const s16x8*)(yr + p1 + d0);
  float* yo = y + (size_t)t * DMODEL + d0;
#pragma unroll
  for (int j = 0; j < 8; ++j)
    yo[j] += w0 * bf2f((u16)a[j]) + w1 * bf2f((u16)b[j]);
}

extern "C" void kernel_launch(void* const* d_in, const int* in_sizes, int n_in,
                              void* d_out, int out_size, void* d_ws, size_t ws_size,
                              hipStream_t stream) {
  const float* x   = (const float*)d_in[0];
  const float* gw  = (const float*)d_in[1];
  const float* wg  = (const float*)d_in[2];
  const float* wu  = (const float*)d_in[3];
  const float* wd  = (const float*)d_in[4];
  const float* wsg = (const float*)d_in[5];
  const float* wsu = (const float*)d_in[6];
  const float* wsd = (const float*)d_in[7];
  float* out = (float*)d_out;

  char* ws = (char*)d_ws;
  size_t o = 0;
  auto alloc = [&](size_t bytes) -> void* {
    void* p = ws + o;
    o += (bytes + 255) & ~(size_t)255;
    return p;
  };
  u16* xb   = (u16*)alloc((size_t)T_TOK * DMODEL * 2);
  u16* wbg  = (u16*)alloc((size_t)NEXP * DFF * DMODEL * 2);
  u16* wbu  = (u16*)alloc((size_t)NEXP * DFF * DMODEL * 2);
  u16* wbd  = (u16*)alloc((size_t)NEXP * DMODEL * DFF * 2);
  u16* wbsg = (u16*)alloc((size_t)DFFS * DMODEL * 2);
  u16* wbsu = (u16*)alloc((size_t)DFFS * DMODEL * 2);
  u16* wbsd = (u16*)alloc((size_t)DMODEL * DFFS * 2);
  u16* P1r  = (u16*)alloc((size_t)NSLOT * DFF * 2);    // h_r (silu fused in GU)
  u16* P1s  = (u16*)alloc((size_t)T_TOK * DFFS * 2);   // h_s
  u16* yr   = (u16*)alloc((size_t)NSLOT * DMODEL * 2);
  float* tkw = (float*)alloc((size_t)T_TOK * 2 * 4);
  int* tki   = (int*)alloc((size_t)T_TOK * 2 * 4);
  int* pos   = (int*)alloc((size_t)T_TOK * 2 * 4);
  int* slot_tok = (int*)alloc((size_t)NSLOT * 4);
  int* counts   = (int*)alloc(64);
  int* offs     = (int*)alloc(64);
  int* cursor   = (int*)alloc(64);
  int* tblGU    = (int*)alloc(GU_GRID * 4);
  int* tblDN    = (int*)alloc(DN_GRID * 4);
  int* nact     = (int*)alloc(64);
  if (o > ws_size) {
    fprintf(stderr, "kernel_launch: ws too small: need %zu have %zu\n", o, ws_size);
    return;
  }

  // --- merged weight conversion (single dispatch, grid-stride) ---
  {
    int n8w = NEXP * DFF * DMODEL / 8;
    int n8s = DFFS * DMODEL / 8;
    k_convert6<<<2048, 256, 0, stream>>>(wg, wbg, n8w, wu, wbu, n8w, wd, wbd, n8w,
                                         wsg, wbsg, n8s, wsu, wbsu, n8s, wsd, wbsd, n8s);
  }

  // --- routing (also produces xb) + schedule tables ---
  k_zero<<<1, 64, 0, stream>>>(counts);
  k_router<<<T_TOK, 256, 0, stream>>>(x, gw, xb, tkw, tki, counts);
  k_scan_sched<<<1, 64, 0, stream>>>(counts, offs, cursor, tblGU, tblDN, nact);
  k_assign<<<(T_TOK + 255) / 256, 256, 0, stream>>>(tki, cursor, pos, slot_tok);

  // --- merged gate/up GEMM with fused silu (routed + shared) ---
  k_gemm8<0><<<GU_GRID, 512, 0, stream>>>(
      tblGU, nact, xb, nullptr, nullptr,
      wbg, wbu, wbd, wbsg, wbsu, wbsd,
      P1r, P1s, yr, out, offs, counts, slot_tok);

  // --- merged down GEMM (routed -> yr, shared -> out) ---
  k_gemm8<1><<<DN_GRID, 512, 0, stream>>>(
      tblDN, nact, xb, P1r, P1s,
      wbg, wbu, wbd, wbsg, wbsu, wbsd,
      P1r, P1s, yr, out, offs, counts, slot_tok);

  // --- combine routed into output ---
  k_combine<<<T_TOK, 256, 0, stream>>>(out, yr, tkw, pos);
}

// Round 12
// 562.312 us; speedup vs baseline: 1.1518x; 1.0060x over previous
//
#include <hip/hip_runtime.h>
#include <stdint.h>
#include <stdio.h>

#define T_TOK 4096
#define DMODEL 2048
#define NEXP 8
#define DFF 1408
#define DFFS 2816
#define NSLOT 8192   // T_TOK * 2

// schedule-table grid bounds (worst case): routed m-blocks sum <= 39
#define GU_GRID (16 * 22 + 39 * 11)   // 781
#define DN_GRID (16 * 8 + 39 * 8)     // 440

typedef unsigned short u16;
typedef short s16x8 __attribute__((ext_vector_type(8)));
typedef unsigned short u16x4 __attribute__((ext_vector_type(4)));
typedef __bf16 bf16x8 __attribute__((ext_vector_type(8)));
typedef float f32x4 __attribute__((ext_vector_type(4)));

__device__ __forceinline__ u16 f2bf(float f) {
  uint32_t u = __builtin_bit_cast(uint32_t, f);
  u += 0x7fffu + ((u >> 16) & 1u);
  return (u16)(u >> 16);
}
__device__ __forceinline__ float bf2f(u16 h) {
  uint32_t u = ((uint32_t)h) << 16;
  return __builtin_bit_cast(float, u);
}

// async global->LDS, 16B per lane; LDS dest = wave-uniform base + lane*16
__device__ __forceinline__ void gl16(const u16* g, u16* l) {
  __builtin_amdgcn_global_load_lds((const __attribute__((address_space(1))) void*)g,
                                   (__attribute__((address_space(3))) void*)l,
                                   16, 0, 0);
}

#define BARRIER() asm volatile("s_barrier" ::: "memory")
#define SBAR()    __builtin_amdgcn_sched_barrier(0)

// ---------------- merged fp32 -> bf16 convert (grid-stride, 8 elems/iter) ----------------
__global__ void k_convert6(const float* __restrict__ s0, u16* __restrict__ d0, int n0,
                           const float* __restrict__ s1, u16* __restrict__ d1, int n1,
                           const float* __restrict__ s2, u16* __restrict__ d2, int n2,
                           const float* __restrict__ s3, u16* __restrict__ d3, int n3,
                           const float* __restrict__ s4, u16* __restrict__ d4, int n4,
                           const float* __restrict__ s5, u16* __restrict__ d5, int n5) {
  int total = n0 + n1 + n2 + n3 + n4 + n5;
  int stride = gridDim.x * 256;
  for (int i = blockIdx.x * 256 + threadIdx.x; i < total; i += stride) {
    const float* s; u16* d; int k = i;
    if (k < n0) { s = s0; d = d0; }
    else { k -= n0;
      if (k < n1) { s = s1; d = d1; }
      else { k -= n1;
        if (k < n2) { s = s2; d = d2; }
        else { k -= n2;
          if (k < n3) { s = s3; d = d3; }
          else { k -= n3;
            if (k < n4) { s = s4; d = d4; }
            else { k -= n4; s = s5; d = d5; }
          }
        }
      }
    }
    float4 a = ((const float4*)s)[2 * k];
    float4 b = ((const float4*)s)[2 * k + 1];
    s16x8 r;
    r[0] = (short)f2bf(a.x); r[1] = (short)f2bf(a.y);
    r[2] = (short)f2bf(a.z); r[3] = (short)f2bf(a.w);
    r[4] = (short)f2bf(b.x); r[5] = (short)f2bf(b.y);
    r[6] = (short)f2bf(b.z); r[7] = (short)f2bf(b.w);
    ((s16x8*)d)[k] = r;
  }
}

__global__ void k_zero(int* __restrict__ counts) {
  if (threadIdx.x < NEXP) counts[threadIdx.x] = 0;
}

// ---------------- router: 4 waves/token, 2 experts/wave, fused x->bf16 ----------------
__global__ void k_router(const float* __restrict__ x, const float* __restrict__ gw,
                         u16* __restrict__ xb,
                         float* __restrict__ tkw, int* __restrict__ tki,
                         int* __restrict__ counts) {
  __shared__ double sm[NEXP];
  int t = blockIdx.x;
  int tid = threadIdx.x;
  int lane = tid & 63, wv = tid >> 6;     // 4 waves
  const float4* xr = (const float4*)(x + (size_t)t * DMODEL);
  const float4* gr = (const float4*)gw;
  int e0 = wv * 2, e1 = e0 + 1;
  double a0 = 0.0, a1 = 0.0;
#pragma unroll
  for (int it = 0; it < DMODEL / 4 / 64; ++it) {   // 8 iters
    int idx = it * 64 + lane;
    float4 xv = xr[idx];
    float4 g0 = gr[e0 * (DMODEL / 4) + idx];
    float4 g1 = gr[e1 * (DMODEL / 4) + idx];
    a0 += (double)xv.x * g0.x + (double)xv.y * g0.y +
          (double)xv.z * g0.z + (double)xv.w * g0.w;
    a1 += (double)xv.x * g1.x + (double)xv.y * g1.y +
          (double)xv.z * g1.z + (double)xv.w * g1.w;
    if (wv == 0) {   // fused x -> bf16 (wave 0 only)
      u16x4 r = { f2bf(xv.x), f2bf(xv.y), f2bf(xv.z), f2bf(xv.w) };
      ((u16x4*)(xb + (size_t)t * DMODEL))[idx] = r;
    }
  }
#pragma unroll
  for (int off = 32; off; off >>= 1) {
    a0 += __shfl_down(a0, off, 64);
    a1 += __shfl_down(a1, off, 64);
  }
  if (lane == 0) { sm[e0] = a0; sm[e1] = a1; }
  __syncthreads();
  if (tid == 0) {
    double acc[NEXP];
#pragma unroll
    for (int e = 0; e < NEXP; ++e) acc[e] = sm[e];
    int i0 = 0; double v0 = acc[0];
    for (int e = 1; e < NEXP; ++e) if (acc[e] > v0) { v0 = acc[e]; i0 = e; }
    int i1 = -1; double v1 = -1e300;
    for (int e = 0; e < NEXP; ++e) if (e != i0 && acc[e] > v1) { v1 = acc[e]; i1 = e; }
    double r = exp(v1 - v0);
    float w0 = (float)(1.0 / (1.0 + r));
    float w1 = 1.0f - w0;
    tkw[2 * t] = w0; tkw[2 * t + 1] = w1;
    tki[2 * t] = i0; tki[2 * t + 1] = i1;
    atomicAdd(&counts[i0], 1);
    atomicAdd(&counts[i1], 1);
  }
}

// ---------------- merged scan + schedule-table builder (round-9 ordering) ----------------
// desc: bit31 = shared flag, bits24-27 = expert, bits12-23 = mb, bits0-11 = nb.
// GU: nb indexes 128-col panels (g+u fused per block). DN: nb indexes 256-col.
// Shared entries FIRST (LPT for DOWN: shared-down blocks have 2x the K).
__global__ void k_scan_sched(const int* __restrict__ counts, int* __restrict__ offs,
                             int* __restrict__ cursor, int* __restrict__ tblGU,
                             int* __restrict__ tblDN, int* __restrict__ nact) {
  if (threadIdx.x != 0 || blockIdx.x != 0) return;
  int s = 0;
  for (int e = 0; e < NEXP; ++e) { offs[e] = s; cursor[e] = s; s += counts[e]; }
  offs[NEXP] = s;
  int g = 0, d = 0;
  for (int m = 0; m < T_TOK / 256; ++m) {
    for (int nb = 0; nb < DFFS / 128; ++nb)
      tblGU[g++] = (int)(0x80000000u | (m << 12) | nb);
    for (int nb = 0; nb < DMODEL / 256; ++nb)
      tblDN[d++] = (int)(0x80000000u | (m << 12) | nb);
  }
  for (int e = 0; e < NEXP; ++e) {
    int mb = (counts[e] + 255) >> 8;
    for (int m = 0; m < mb; ++m) {
      for (int nb = 0; nb < DFF / 128; ++nb)
        tblGU[g++] = (e << 24) | (m << 12) | nb;
      for (int nb = 0; nb < DMODEL / 256; ++nb)
        tblDN[d++] = (e << 24) | (m << 12) | nb;
    }
  }
  nact[0] = g; nact[1] = d;
}

__global__ void k_assign(const int* __restrict__ tki, int* __restrict__ cursor,
                         int* __restrict__ pos, int* __restrict__ slot_tok) {
  int t = blockIdx.x * 256 + threadIdx.x;
  if (t >= T_TOK) return;
#pragma unroll
  for (int k = 0; k < 2; ++k) {
    int e = tki[2 * t + k];
    int p = atomicAdd(&cursor[e], 1);
    pos[2 * t + k] = p;
    slot_tok[p] = t;
  }
}

// ---------------- 256-row NT bf16 GEMM, single-sync balanced pipeline, fused-silu GU --
// PHASE 0 = gate/up+silu fused: 256m x 128 cols, B-tile rows interleaved;
//   epilogue computes h = silu(g)*u in-register, writes h only.
// PHASE 1 = merged down (runtime K = 1408/2816), 256x256, writes yr / out.
// 512 thr = 8 waves (2M x 4N), BK=64, LDS 2 x 64KB dbuf, T2 XOR-swizzle.
// ONE sync point per tile (s2): lgkm(0) [buf reads done] + vmcnt(0) [batch(t+1),
// issued 4 phases earlier at (t-1).s2, complete] + barrier. Read distribution
// balanced 4/8/8/4 so every batch has >=1 phase of MFMA on both sides:
//   s0: read rB23(t);                        MFMA q00 (rAa x rB01)
//   s1: read rAb(t);                         MFMA q01 (rAa x rB23)  [rAa dead]
//   s2: lgkm0+vm0+BAR; stage8(t+2)->buf; read rAa'(t+1)<-nbuf; MFMA q10 (rAb x rB01) [rB01 dead]
//   s3: read rB01'(t+1)<-nbuf;               MFMA q11 (rAb x rB23)
template <int PHASE>
__launch_bounds__(512, 2)
__global__ void k_gemm8(const int* __restrict__ tbl, const int* __restrict__ nact,
                        const u16* __restrict__ xb,
                        const u16* __restrict__ hr, const u16* __restrict__ hs,
                        const u16* __restrict__ wbg, const u16* __restrict__ wbu,
                        const u16* __restrict__ wbd,
                        const u16* __restrict__ wbsg, const u16* __restrict__ wbsu,
                        const u16* __restrict__ wbsd,
                        u16* __restrict__ P1r, u16* __restrict__ P1s,
                        u16* __restrict__ yr, float* __restrict__ out,
                        const int* __restrict__ offs, const int* __restrict__ counts,
                        const int* __restrict__ slot_tok) {
  __shared__ __attribute__((aligned(16))) u16 lds[2 * 32768];  // 128 KiB

  if ((int)blockIdx.x >= nact[PHASE]) return;
  const int desc = tbl[blockIdx.x];
  const bool shrd = desc < 0;
  const int e = (desc >> 24) & 0xF;
  const int m0 = ((desc >> 12) & 0xFFF) * 256;
  const int n0 = (desc & 0xFFF) * (PHASE == 0 ? 128 : 256);

  const u16 *A, *Bg, *Bu;
  u16* C1;
  float* OF = nullptr;
  int base, cnt, HS, K;
  bool gather = false;
  if constexpr (PHASE == 0) {
    K = DMODEL;
    if (shrd) {
      A = xb; base = 0; cnt = T_TOK;
      Bg = wbsg; Bu = wbsu; C1 = P1s; HS = DFFS;
    } else {
      A = xb; gather = true; base = offs[e]; cnt = counts[e];
      size_t es = (size_t)e * DFF * DMODEL;
      Bg = wbg + es; Bu = wbu + es; C1 = P1r; HS = DFF;
    }
  } else {
    HS = DMODEL;
    if (shrd) {
      A = hs; base = 0; cnt = T_TOK; K = DFFS;
      Bg = Bu = wbsd; OF = out; C1 = nullptr;
    } else {
      A = hr; base = offs[e]; cnt = counts[e]; K = DFF;
      Bg = Bu = wbd + (size_t)e * DMODEL * DFF; C1 = yr;
    }
  }
  const int NT = K >> 6;

  int tid = threadIdx.x;
  int lane = tid & 63, wv = tid >> 6;
  int wm = wv >> 2, wn = wv & 3;
  int fr = lane & 15, fq = lane >> 4;

  // --- staging source pointers: 4 A-slabs + 4 B-slabs (64 rows each)
  int srow = tid >> 3;                     // wv*8 + (lane>>3), 0..63
  int sslot = (tid & 7) ^ (srow & 7);      // T2 pre-swizzle (involution)
  const u16* ap[4]; const u16* bp[4];
#pragma unroll
  for (int h = 0; h < 4; ++h) {
    int r = h * 64 + srow;                 // tile row 0..255
    int ra = m0 + r; ra = ra < cnt ? ra : cnt - 1;
    int ga = gather ? slot_tok[base + ra] : base + ra;
    ap[h] = A + (size_t)ga * K + sslot * 8;
    const u16* bb;
    if constexpr (PHASE == 0) {
      // interleaved g/u B-tile: row r -> wave wn_r = r>>6, s = r&63;
      // s<32: wg col n0+wn_r*32+s ; s>=32: wu col n0+wn_r*32+(s-32)
      int wnr = r >> 6, s = r & 63;
      int col = n0 + wnr * 32 + (s & 31);
      bb = (s < 32 ? Bg : Bu) + (size_t)col * K;
    } else {
      bb = Bg + (size_t)(n0 + r) * K;
    }
    bp[h] = bb + sslot * 8;
  }

#define STG_A(h, bufi, kt) gl16(ap[h] + (size_t)(kt) * 64, \
                                lds + (bufi) * 32768 + (h) * 4096 + wv * 512)
#define STG_B(h, bufi, kt) gl16(bp[h] + (size_t)(kt) * 64, \
                                lds + (bufi) * 32768 + 16384 + (h) * 4096 + wv * 512)
#define STG8(bufi, kt) { STG_A(0, bufi, kt); STG_A(1, bufi, kt); \
                         STG_A(2, bufi, kt); STG_A(3, bufi, kt); \
                         STG_B(0, bufi, kt); STG_B(1, bufi, kt); \
                         STG_B(2, bufi, kt); STG_B(3, bufi, kt); }

  // --- read bases (u16 units); swizzled k-slot is lane-constant per ks
  int sKs0 = ((0 + fq) ^ (fr & 7)) * 8;
  int sKs1 = ((4 + fq) ^ (fr & 7)) * 8;
  int aBase = wm * 8192 + fr * 64;                                   // + i*1024
  int bBase = 16384 + (wn >> 1) * 8192 + ((wn & 1) * 64 + fr) * 64;  // + j*1024

  f32x4 acc[8][4];
#pragma unroll
  for (int i = 0; i < 8; ++i)
#pragma unroll
    for (int j = 0; j < 4; ++j) acc[i][j] = (f32x4){0.f, 0.f, 0.f, 0.f};

  // prologue: stage tile0 -> buf0 and tile1 -> buf1; drain tile0 only
  STG8(0, 0);
  if (NT > 1) { STG8(1, 1); asm volatile("s_waitcnt vmcnt(8)" ::: "memory"); }
  else        {             asm volatile("s_waitcnt vmcnt(0)" ::: "memory"); }
  BARRIER();
  SBAR();

  bf16x8 rAa[4][2], rAb[4][2], rB01[2][2], rB23[2][2];
#pragma unroll
  for (int il = 0; il < 4; ++il) {
    rAa[il][0] = *(const bf16x8*)(lds + aBase + il * 1024 + sKs0);
    rAa[il][1] = *(const bf16x8*)(lds + aBase + il * 1024 + sKs1);
  }
#pragma unroll
  for (int jl = 0; jl < 2; ++jl) {
    rB01[jl][0] = *(const bf16x8*)(lds + bBase + jl * 1024 + sKs0);
    rB01[jl][1] = *(const bf16x8*)(lds + bBase + jl * 1024 + sKs1);
  }

  for (int t = 0; t < NT; ++t) {
    const int buf = t & 1;
    const u16* lbuf = lds + buf * 32768;
    const u16* lbufN = lds + (buf ^ 1) * 32768;
    const bool hn1 = (t + 1) < NT, hn2 = (t + 2) < NT;

    // ---- s0: read rB23(t); MFMA q00 (rAa x rB01)
#pragma unroll
    for (int jl = 0; jl < 2; ++jl) {
      rB23[jl][0] = *(const bf16x8*)(lbuf + bBase + (2 + jl) * 1024 + sKs0);
      rB23[jl][1] = *(const bf16x8*)(lbuf + bBase + (2 + jl) * 1024 + sKs1);
    }
    __builtin_amdgcn_s_setprio(1);
#pragma unroll
    for (int il = 0; il < 4; ++il)
#pragma unroll
      for (int jl = 0; jl < 2; ++jl) {
        acc[il][jl] = __builtin_amdgcn_mfma_f32_16x16x32_bf16(rAa[il][0], rB01[jl][0], acc[il][jl], 0, 0, 0);
        acc[il][jl] = __builtin_amdgcn_mfma_f32_16x16x32_bf16(rAa[il][1], rB01[jl][1], acc[il][jl], 0, 0, 0);
      }
    __builtin_amdgcn_s_setprio(0);

    // ---- s1: read rAb(t); MFMA q01 (rAa x rB23) [rAa dead after]
#pragma unroll
    for (int il = 0; il < 4; ++il) {
      rAb[il][0] = *(const bf16x8*)(lbuf + aBase + (4 + il) * 1024 + sKs0);
      rAb[il][1] = *(const bf16x8*)(lbuf + aBase + (4 + il) * 1024 + sKs1);
    }
    __builtin_amdgcn_s_setprio(1);
#pragma unroll
    for (int il = 0; il < 4; ++il)
#pragma unroll
      for (int jl = 0; jl < 2; ++jl) {
        acc[il][2 + jl] = __builtin_amdgcn_mfma_f32_16x16x32_bf16(rAa[il][0], rB23[jl][0], acc[il][2 + jl], 0, 0, 0);
        acc[il][2 + jl] = __builtin_amdgcn_mfma_f32_16x16x32_bf16(rAa[il][1], rB23[jl][1], acc[il][2 + jl], 0, 0, 0);
      }
    __builtin_amdgcn_s_setprio(0);

    // ---- s2: SINGLE SYNC {lgkm(0): buf reads done; vmcnt(0): batch(t+1) resident,
    //          4-phase lead; barrier}; stage8(t+2)->buf; read rAa'(t+1); MFMA q10
    asm volatile("s_waitcnt lgkmcnt(0) vmcnt(0)" ::: "memory");
    BARRIER();
    SBAR();
    if (hn2) STG8(buf, t + 2);
    if (hn1) {
#pragma unroll
      for (int il = 0; il < 4; ++il) {
        rAa[il][0] = *(const bf16x8*)(lbufN + aBase + il * 1024 + sKs0);
        rAa[il][1] = *(const bf16x8*)(lbufN + aBase + il * 1024 + sKs1);
      }
    }
    __builtin_amdgcn_s_setprio(1);
#pragma unroll
    for (int il = 0; il < 4; ++il)
#pragma unroll
      for (int jl = 0; jl < 2; ++jl) {
        acc[4 + il][jl] = __builtin_amdgcn_mfma_f32_16x16x32_bf16(rAb[il][0], rB01[jl][0], acc[4 + il][jl], 0, 0, 0);
        acc[4 + il][jl] = __builtin_amdgcn_mfma_f32_16x16x32_bf16(rAb[il][1], rB01[jl][1], acc[4 + il][jl], 0, 0, 0);
      }
    __builtin_amdgcn_s_setprio(0);

    // ---- s3: read rB01'(t+1); MFMA q11 (rAb x rB23)
    if (hn1) {
#pragma unroll
      for (int jl = 0; jl < 2; ++jl) {
        rB01[jl][0] = *(const bf16x8*)(lbufN + bBase + jl * 1024 + sKs0);
        rB01[jl][1] = *(const bf16x8*)(lbufN + bBase + jl * 1024 + sKs1);
      }
    }
    __builtin_amdgcn_s_setprio(1);
#pragma unroll
    for (int il = 0; il < 4; ++il)
#pragma unroll
      for (int jl = 0; jl < 2; ++jl) {
        acc[4 + il][2 + jl] = __builtin_amdgcn_mfma_f32_16x16x32_bf16(rAb[il][0], rB23[jl][0], acc[4 + il][2 + jl], 0, 0, 0);
        acc[4 + il][2 + jl] = __builtin_amdgcn_mfma_f32_16x16x32_bf16(rAb[il][1], rB23[jl][1], acc[4 + il][2 + jl], 0, 0, 0);
      }
    __builtin_amdgcn_s_setprio(0);
  }
#undef STG_A
#undef STG_B
#undef STG8

  // --- epilogue ---
#pragma unroll
  for (int i = 0; i < 8; ++i) {
    int row_t = wm * 128 + i * 16 + fq * 4;
#pragma unroll
    for (int r = 0; r < 4; ++r) {
      int m = m0 + row_t + r;
      if (m >= cnt) continue;
      size_t rowoff = (size_t)(base + m) * (size_t)HS;
      if constexpr (PHASE == 0) {
        // h = silu(g) * u ; g = acc[i][jl], u = acc[i][2+jl], col = n0+wn*32+jl*16+fr
#pragma unroll
        for (int jl = 0; jl < 2; ++jl) {
          float g = acc[i][jl][r];
          float u = acc[i][2 + jl][r];
          float hval = (g / (1.f + __expf(-g))) * u;
          C1[rowoff + (n0 + wn * 32 + jl * 16 + fr)] = f2bf(hval);
        }
      } else {
#pragma unroll
        for (int j = 0; j < 4; ++j) {
          int col_t = n0 + wn * 64 + j * 16 + fr;
          float v = acc[i][j][r];
          if (shrd) OF[rowoff + col_t] = v;
          else      C1[rowoff + col_t] = f2bf(v);
        }
      }
    }
  }
}

// ---------------- y[t] += w0*yr[pos0] + w1*yr[pos1] ----------------
__global__ void k_combine(float* __restrict__ y, const u16* __restrict__ yr,
                          const float* __restrict__ tkw, const int* __restrict__ pos) {
  int t = blockIdx.x;
  int i = threadIdx.x;
  float w0 = tkw[2 * t], w1 = tkw[2 * t + 1];
  size_t p0 = (size_t)pos[2 * t] * DMODEL, p1 = (size_t)pos[2 * t + 1] * DMODEL;
  int d0 = i * 8;
  s16x8 a = *(const s16x8*)(yr + p0 + d0);
  s16x8 b = *(const s16x8*)(yr + p1 + d0);
  float* yo = y + (size_t)t * DMODEL + d0;
#pragma unroll
  for (int j = 0; j < 8; ++j)
    yo[j] += w0 * bf2f((u16)a[j]) + w1 * bf2f((u16)b[j]);
}

extern "C" void kernel_launch(void* const* d_in, const int* in_sizes, int n_in,
                              void* d_out, int out_size, void* d_ws, size_t ws_size,
                              hipStream_t stream) {
  const float* x   = (const float*)d_in[0];
  const float* gw  = (const float*)d_in[1];
  const float* wg  = (const float*)d_in[2];
  const float* wu  = (const float*)d_in[3];
  const float* wd  = (const float*)d_in[4];
  const float* wsg = (const float*)d_in[5];
  const float* wsu = (const float*)d_in[6];
  const float* wsd = (const float*)d_in[7];
  float* out = (float*)d_out;

  char* ws = (char*)d_ws;
  size_t o = 0;
  auto alloc = [&](size_t bytes) -> void* {
    void* p = ws + o;
    o += (bytes + 255) & ~(size_t)255;
    return p;
  };
  u16* xb   = (u16*)alloc((size_t)T_TOK * DMODEL * 2);
  u16* wbg  = (u16*)alloc((size_t)NEXP * DFF * DMODEL * 2);
  u16* wbu  = (u16*)alloc((size_t)NEXP * DFF * DMODEL * 2);
  u16* wbd  = (u16*)alloc((size_t)NEXP * DMODEL * DFF * 2);
  u16* wbsg = (u16*)alloc((size_t)DFFS * DMODEL * 2);
  u16* wbsu = (u16*)alloc((size_t)DFFS * DMODEL * 2);
  u16* wbsd = (u16*)alloc((size_t)DMODEL * DFFS * 2);
  u16* P1r  = (u16*)alloc((size_t)NSLOT * DFF * 2);    // h_r (silu fused in GU)
  u16* P1s  = (u16*)alloc((size_t)T_TOK * DFFS * 2);   // h_s
  u16* yr   = (u16*)alloc((size_t)NSLOT * DMODEL * 2);
  float* tkw = (float*)alloc((size_t)T_TOK * 2 * 4);
  int* tki   = (int*)alloc((size_t)T_TOK * 2 * 4);
  int* pos   = (int*)alloc((size_t)T_TOK * 2 * 4);
  int* slot_tok = (int*)alloc((size_t)NSLOT * 4);
  int* counts   = (int*)alloc(64);
  int* offs     = (int*)alloc(64);
  int* cursor   = (int*)alloc(64);
  int* tblGU    = (int*)alloc(GU_GRID * 4);
  int* tblDN    = (int*)alloc(DN_GRID * 4);
  int* nact     = (int*)alloc(64);
  if (o > ws_size) {
    fprintf(stderr, "kernel_launch: ws too small: need %zu have %zu\n", o, ws_size);
    return;
  }

  // --- merged weight conversion (single dispatch, grid-stride) ---
  {
    int n8w = NEXP * DFF * DMODEL / 8;
    int n8s = DFFS * DMODEL / 8;
    k_convert6<<<2048, 256, 0, stream>>>(wg, wbg, n8w, wu, wbu, n8w, wd, wbd, n8w,
                                         wsg, wbsg, n8s, wsu, wbsu, n8s, wsd, wbsd, n8s);
  }

  // --- routing (also produces xb) + schedule tables ---
  k_zero<<<1, 64, 0, stream>>>(counts);
  k_router<<<T_TOK, 256, 0, stream>>>(x, gw, xb, tkw, tki, counts);
  k_scan_sched<<<1, 64, 0, stream>>>(counts, offs, cursor, tblGU, tblDN, nact);
  k_assign<<<(T_TOK + 255) / 256, 256, 0, stream>>>(tki, cursor, pos, slot_tok);

  // --- merged gate/up GEMM with fused silu (routed + shared) ---
  k_gemm8<0><<<GU_GRID, 512, 0, stream>>>(
      tblGU, nact, xb, nullptr, nullptr,
      wbg, wbu, wbd, wbsg, wbsu, wbsd,
      P1r, P1s, yr, out, offs, counts, slot_tok);

  // --- merged down GEMM (routed -> yr, shared -> out) ---
  k_gemm8<1><<<DN_GRID, 512, 0, stream>>>(
      tblDN, nact, xb, P1r, P1s,
      wbg, wbu, wbd, wbsg, wbsu, wbsd,
      P1r, P1s, yr, out, offs, counts, slot_tok);

  // --- combine routed into output ---
  k_combine<<<T_TOK, 256, 0, stream>>>(out, yr, tkw, pos);
}

// Round 13
// 534.926 us; speedup vs baseline: 1.2107x; 1.0512x over previous
//
#include <hip/hip_runtime.h>
#include <stdint.h>
#include <stdio.h>

#define T_TOK 4096
#define DMODEL 2048
#define NEXP 8
#define DFF 1408
#define DFFS 2816
#define NSLOT 8192   // T_TOK * 2

// schedule-table grid bounds (worst case): routed m-blocks sum <= 39
#define GU_GRID (16 * 22 + 39 * 11)   // 781
#define DN_GRID (16 * 8 + 39 * 8)     // 440
#define CONV_GU 1024                  // gate/up convert blocks appended to router
#define CONV_DN 512                   // down convert blocks appended to GU gemm

typedef unsigned short u16;
typedef short s16x8 __attribute__((ext_vector_type(8)));
typedef unsigned short u16x4 __attribute__((ext_vector_type(4)));
typedef __bf16 bf16x8 __attribute__((ext_vector_type(8)));
typedef float f32x4 __attribute__((ext_vector_type(4)));

__device__ __forceinline__ u16 f2bf(float f) {
  uint32_t u = __builtin_bit_cast(uint32_t, f);
  u += 0x7fffu + ((u >> 16) & 1u);
  return (u16)(u >> 16);
}
__device__ __forceinline__ float bf2f(u16 h) {
  uint32_t u = ((uint32_t)h) << 16;
  return __builtin_bit_cast(float, u);
}

// async global->LDS, 16B per lane; LDS dest = wave-uniform base + lane*16
__device__ __forceinline__ void gl16(const u16* g, u16* l) {
  __builtin_amdgcn_global_load_lds((const __attribute__((address_space(1))) void*)g,
                                   (__attribute__((address_space(3))) void*)l,
                                   16, 0, 0);
}

#define BARRIER() asm volatile("s_barrier" ::: "memory")
#define SBAR()    __builtin_amdgcn_sched_barrier(0)

__device__ __forceinline__ void conv8(const float* __restrict__ s, u16* __restrict__ d,
                                      long k) {
  float4 a = ((const float4*)s)[2 * k];
  float4 b = ((const float4*)s)[2 * k + 1];
  s16x8 r;
  r[0] = (short)f2bf(a.x); r[1] = (short)f2bf(a.y);
  r[2] = (short)f2bf(a.z); r[3] = (short)f2bf(a.w);
  r[4] = (short)f2bf(b.x); r[5] = (short)f2bf(b.y);
  r[6] = (short)f2bf(b.z); r[7] = (short)f2bf(b.w);
  ((s16x8*)d)[k] = r;
}

__global__ void k_zero(int* __restrict__ counts) {
  if (threadIdx.x < NEXP) counts[threadIdx.x] = 0;
}

// ---------------- router (4 waves/token, fused x->bf16) + gate/up convert backfill ----
// Blocks [0, T_TOK): router. Blocks [T_TOK, T_TOK+CONV_GU): grid-stride fp32->bf16
// convert of wg|wu|wsg|wsu (tiny blocks backfill idle CUs; BW-bound ~55us hides the
// router's latency-bound 15us).
__global__ void k_router(const float* __restrict__ x, const float* __restrict__ gw,
                         u16* __restrict__ xb,
                         float* __restrict__ tkw, int* __restrict__ tki,
                         int* __restrict__ counts,
                         const float* __restrict__ wgF, u16* __restrict__ wbg,
                         const float* __restrict__ wuF, u16* __restrict__ wbu,
                         const float* __restrict__ wsgF, u16* __restrict__ wbsg,
                         const float* __restrict__ wsuF, u16* __restrict__ wbsu) {
  if (blockIdx.x >= T_TOK) {   // ---- convert path ----
    const long N1 = (long)NEXP * DFF * DMODEL / 8;   // 2883584
    const long NS = (long)DFFS * DMODEL / 8;         // 720896
    const long total = 2 * N1 + 2 * NS;
    const long stride = (long)CONV_GU * 256;
    for (long i = (long)(blockIdx.x - T_TOK) * 256 + threadIdx.x; i < total; i += stride) {
      long k = i;
      if (k < N1)            conv8(wgF, wbg, k);
      else { k -= N1;
        if (k < N1)          conv8(wuF, wbu, k);
        else { k -= N1;
          if (k < NS)        conv8(wsgF, wbsg, k);
          else               conv8(wsuF, wbsu, k - NS);
        }
      }
    }
    return;
  }
  __shared__ double sm[NEXP];
  int t = blockIdx.x;
  int tid = threadIdx.x;
  int lane = tid & 63, wv = tid >> 6;     // 4 waves
  const float4* xr = (const float4*)(x + (size_t)t * DMODEL);
  const float4* gr = (const float4*)gw;
  int e0 = wv * 2, e1 = e0 + 1;
  double a0 = 0.0, a1 = 0.0;
#pragma unroll
  for (int it = 0; it < DMODEL / 4 / 64; ++it) {   // 8 iters
    int idx = it * 64 + lane;
    float4 xv = xr[idx];
    float4 g0 = gr[e0 * (DMODEL / 4) + idx];
    float4 g1 = gr[e1 * (DMODEL / 4) + idx];
    a0 += (double)xv.x * g0.x + (double)xv.y * g0.y +
          (double)xv.z * g0.z + (double)xv.w * g0.w;
    a1 += (double)xv.x * g1.x + (double)xv.y * g1.y +
          (double)xv.z * g1.z + (double)xv.w * g1.w;
    if (wv == 0) {   // fused x -> bf16 (wave 0 only)
      u16x4 r = { f2bf(xv.x), f2bf(xv.y), f2bf(xv.z), f2bf(xv.w) };
      ((u16x4*)(xb + (size_t)t * DMODEL))[idx] = r;
    }
  }
#pragma unroll
  for (int off = 32; off; off >>= 1) {
    a0 += __shfl_down(a0, off, 64);
    a1 += __shfl_down(a1, off, 64);
  }
  if (lane == 0) { sm[e0] = a0; sm[e1] = a1; }
  __syncthreads();
  if (tid == 0) {
    double acc[NEXP];
#pragma unroll
    for (int e = 0; e < NEXP; ++e) acc[e] = sm[e];
    int i0 = 0; double v0 = acc[0];
    for (int e = 1; e < NEXP; ++e) if (acc[e] > v0) { v0 = acc[e]; i0 = e; }
    int i1 = -1; double v1 = -1e300;
    for (int e = 0; e < NEXP; ++e) if (e != i0 && acc[e] > v1) { v1 = acc[e]; i1 = e; }
    double r = exp(v1 - v0);
    float w0 = (float)(1.0 / (1.0 + r));
    float w1 = 1.0f - w0;
    tkw[2 * t] = w0; tkw[2 * t + 1] = w1;
    tki[2 * t] = i0; tki[2 * t + 1] = i1;
    atomicAdd(&counts[i0], 1);
    atomicAdd(&counts[i1], 1);
  }
}

// ---------------- merged scan + schedule-table builder (round-9 ordering) ----------------
// desc: bit31 = shared flag, bits24-27 = expert, bits12-23 = mb, bits0-11 = nb.
// GU: nb indexes 128-col panels (g+u fused per block). DN: nb indexes 256-col.
// Shared entries FIRST (LPT for DOWN: shared-down blocks have 2x the K).
__global__ void k_scan_sched(const int* __restrict__ counts, int* __restrict__ offs,
                             int* __restrict__ cursor, int* __restrict__ tblGU,
                             int* __restrict__ tblDN, int* __restrict__ nact) {
  if (threadIdx.x != 0 || blockIdx.x != 0) return;
  int s = 0;
  for (int e = 0; e < NEXP; ++e) { offs[e] = s; cursor[e] = s; s += counts[e]; }
  offs[NEXP] = s;
  int g = 0, d = 0;
  for (int m = 0; m < T_TOK / 256; ++m) {
    for (int nb = 0; nb < DFFS / 128; ++nb)
      tblGU[g++] = (int)(0x80000000u | (m << 12) | nb);
    for (int nb = 0; nb < DMODEL / 256; ++nb)
      tblDN[d++] = (int)(0x80000000u | (m << 12) | nb);
  }
  for (int e = 0; e < NEXP; ++e) {
    int mb = (counts[e] + 255) >> 8;
    for (int m = 0; m < mb; ++m) {
      for (int nb = 0; nb < DFF / 128; ++nb)
        tblGU[g++] = (e << 24) | (m << 12) | nb;
      for (int nb = 0; nb < DMODEL / 256; ++nb)
        tblDN[d++] = (e << 24) | (m << 12) | nb;
    }
  }
  nact[0] = g; nact[1] = d;
}

__global__ void k_assign(const int* __restrict__ tki, int* __restrict__ cursor,
                         int* __restrict__ pos, int* __restrict__ slot_tok) {
  int t = blockIdx.x * 256 + threadIdx.x;
  if (t >= T_TOK) return;
#pragma unroll
  for (int k = 0; k < 2; ++k) {
    int e = tki[2 * t + k];
    int p = atomicAdd(&cursor[e], 1);
    pos[2 * t + k] = p;
    slot_tok[p] = t;
  }
}

// ---------------- 256-row NT bf16 GEMM, reads-lead pipeline (round-9), fused-silu GU --
// PHASE 0 = gate/up+silu fused: 256m x 128 cols, B-tile rows interleaved;
//   epilogue computes h = silu(g)*u in-register, writes h only.
//   Blocks >= GU_GRID: backfill fp32->bf16 convert of down weights (wd|wsd) --
//   tiny blocks stream through CUs left idle by the GEMM's partial last round.
// PHASE 1 = merged down (runtime K = 1408/2816), 256x256, writes yr / out.
// 512 thr = 8 waves (2M x 4N), BK=64, LDS 2 x 64KB dbuf, T2 XOR-swizzle.
template <int PHASE>
__launch_bounds__(512, 2)
__global__ void k_gemm8(const int* __restrict__ tbl, const int* __restrict__ nact,
                        const u16* __restrict__ xb,
                        const u16* __restrict__ hr, const u16* __restrict__ hs,
                        const u16* __restrict__ wbg, const u16* __restrict__ wbu,
                        const u16* __restrict__ wbd,
                        const u16* __restrict__ wbsg, const u16* __restrict__ wbsu,
                        const u16* __restrict__ wbsd,
                        const float* __restrict__ wdF, const float* __restrict__ wsdF,
                        u16* __restrict__ wbdW, u16* __restrict__ wbsdW,
                        u16* __restrict__ P1r, u16* __restrict__ P1s,
                        u16* __restrict__ yr, float* __restrict__ out,
                        const int* __restrict__ offs, const int* __restrict__ counts,
                        const int* __restrict__ slot_tok) {
  __shared__ __attribute__((aligned(16))) u16 lds[2 * 32768];  // 128 KiB

  if constexpr (PHASE == 0) {
    if ((int)blockIdx.x >= GU_GRID) {   // ---- down-weight convert backfill ----
      const long N1 = (long)NEXP * DMODEL * DFF / 8;   // 2883584
      const long NS = (long)DMODEL * DFFS / 8;         // 720896
      const long total = N1 + NS;
      const long stride = (long)CONV_DN * 512;
      for (long i = (long)(blockIdx.x - GU_GRID) * 512 + threadIdx.x; i < total;
           i += stride) {
        if (i < N1) conv8(wdF, wbdW, i);
        else        conv8(wsdF, wbsdW, i - N1);
      }
      return;
    }
  }
  if ((int)blockIdx.x >= nact[PHASE]) return;
  const int desc = tbl[blockIdx.x];
  const bool shrd = desc < 0;
  const int e = (desc >> 24) & 0xF;
  const int m0 = ((desc >> 12) & 0xFFF) * 256;
  const int n0 = (desc & 0xFFF) * (PHASE == 0 ? 128 : 256);

  const u16 *A, *Bg, *Bu;
  u16* C1;
  float* OF = nullptr;
  int base, cnt, HS, K;
  bool gather = false;
  if constexpr (PHASE == 0) {
    K = DMODEL;
    if (shrd) {
      A = xb; base = 0; cnt = T_TOK;
      Bg = wbsg; Bu = wbsu; C1 = P1s; HS = DFFS;
    } else {
      A = xb; gather = true; base = offs[e]; cnt = counts[e];
      size_t es = (size_t)e * DFF * DMODEL;
      Bg = wbg + es; Bu = wbu + es; C1 = P1r; HS = DFF;
    }
  } else {
    HS = DMODEL;
    if (shrd) {
      A = hs; base = 0; cnt = T_TOK; K = DFFS;
      Bg = Bu = wbsd; OF = out; C1 = nullptr;
    } else {
      A = hr; base = offs[e]; cnt = counts[e]; K = DFF;
      Bg = Bu = wbd + (size_t)e * DMODEL * DFF; C1 = yr;
    }
  }
  const int NT = K >> 6;

  int tid = threadIdx.x;
  int lane = tid & 63, wv = tid >> 6;
  int wm = wv >> 2, wn = wv & 3;
  int fr = lane & 15, fq = lane >> 4;

  // --- staging source pointers: 4 A-slabs + 4 B-slabs (64 rows each)
  int srow = tid >> 3;                     // wv*8 + (lane>>3), 0..63
  int sslot = (tid & 7) ^ (srow & 7);      // T2 pre-swizzle (involution)
  const u16* ap[4]; const u16* bp[4];
#pragma unroll
  for (int h = 0; h < 4; ++h) {
    int r = h * 64 + srow;                 // tile row 0..255
    int ra = m0 + r; ra = ra < cnt ? ra : cnt - 1;
    int ga = gather ? slot_tok[base + ra] : base + ra;
    ap[h] = A + (size_t)ga * K + sslot * 8;
    const u16* bb;
    if constexpr (PHASE == 0) {
      // interleaved g/u B-tile: row r -> wave wn_r = r>>6, s = r&63;
      // s<32: wg col n0+wn_r*32+s ; s>=32: wu col n0+wn_r*32+(s-32)
      int wnr = r >> 6, s = r & 63;
      int col = n0 + wnr * 32 + (s & 31);
      bb = (s < 32 ? Bg : Bu) + (size_t)col * K;
    } else {
      bb = Bg + (size_t)(n0 + r) * K;
    }
    bp[h] = bb + sslot * 8;
  }

#define STG_A(h, bufi, kt) gl16(ap[h] + (size_t)(kt) * 64, \
                                lds + (bufi) * 32768 + (h) * 4096 + wv * 512)
#define STG_B(h, bufi, kt) gl16(bp[h] + (size_t)(kt) * 64, \
                                lds + (bufi) * 32768 + 16384 + (h) * 4096 + wv * 512)

  // --- read bases (u16 units); swizzled k-slot is lane-constant per ks
  int sKs0 = ((0 + fq) ^ (fr & 7)) * 8;
  int sKs1 = ((4 + fq) ^ (fr & 7)) * 8;
  int aBase = wm * 8192 + fr * 64;                                   // + i*1024
  int bBase = 16384 + (wn >> 1) * 8192 + ((wn & 1) * 64 + fr) * 64;  // + j*1024

  f32x4 acc[8][4];
#pragma unroll
  for (int i = 0; i < 8; ++i)
#pragma unroll
    for (int j = 0; j < 4; ++j) acc[i][j] = (f32x4){0.f, 0.f, 0.f, 0.f};

  // prologue: full tile0 + A-slabs of tile1
  STG_A(0, 0, 0); STG_A(1, 0, 0); STG_A(2, 0, 0); STG_A(3, 0, 0);
  STG_B(0, 0, 0); STG_B(1, 0, 0); STG_B(2, 0, 0); STG_B(3, 0, 0);
  if (NT > 1) { STG_A(0, 1, 1); STG_A(1, 1, 1); STG_A(2, 1, 1); STG_A(3, 1, 1); }
  if (NT > 1) asm volatile("s_waitcnt vmcnt(4)" ::: "memory");
  else        asm volatile("s_waitcnt vmcnt(0)" ::: "memory");
  BARRIER();
  SBAR();

  bf16x8 rAa[4][2], rAb[4][2], rB01[2][2], rB23[2][2];
#pragma unroll
  for (int il = 0; il < 4; ++il) {
    rAa[il][0] = *(const bf16x8*)(lds + aBase + il * 1024 + sKs0);
    rAa[il][1] = *(const bf16x8*)(lds + aBase + il * 1024 + sKs1);
  }
#pragma unroll
  for (int jl = 0; jl < 2; ++jl) {
    rB01[jl][0] = *(const bf16x8*)(lds + bBase + jl * 1024 + sKs0);
    rB01[jl][1] = *(const bf16x8*)(lds + bBase + jl * 1024 + sKs1);
  }

  for (int t = 0; t < NT; ++t) {
    const int buf = t & 1, nbuf = buf ^ 1;
    const u16* lbuf = lds + buf * 32768;
    const u16* lbufN = lds + nbuf * 32768;
    const bool hn1 = (t + 1) < NT, hn2 = (t + 2) < NT;

    // ---- s0: read B23(t); stage B0,B1(t+1)->nbuf; MFMA mq0 x nq0
#pragma unroll
    for (int jl = 0; jl < 2; ++jl) {
      rB23[jl][0] = *(const bf16x8*)(lbuf + bBase + (2 + jl) * 1024 + sKs0);
      rB23[jl][1] = *(const bf16x8*)(lbuf + bBase + (2 + jl) * 1024 + sKs1);
    }
    if (hn1) { STG_B(0, nbuf, t + 1); STG_B(1, nbuf, t + 1); }
    __builtin_amdgcn_s_setprio(1);
#pragma unroll
    for (int il = 0; il < 4; ++il)
#pragma unroll
      for (int jl = 0; jl < 2; ++jl) {
        acc[il][jl] = __builtin_amdgcn_mfma_f32_16x16x32_bf16(rAa[il][0], rB01[jl][0], acc[il][jl], 0, 0, 0);
        acc[il][jl] = __builtin_amdgcn_mfma_f32_16x16x32_bf16(rAa[il][1], rB01[jl][1], acc[il][jl], 0, 0, 0);
      }
    __builtin_amdgcn_s_setprio(0);

    // ---- s1: read A13(t); stage B2,B3(t+1)->nbuf; MFMA mq0 x nq1
#pragma unroll
    for (int il = 0; il < 4; ++il) {
      rAb[il][0] = *(const bf16x8*)(lbuf + aBase + (4 + il) * 1024 + sKs0);
      rAb[il][1] = *(const bf16x8*)(lbuf + aBase + (4 + il) * 1024 + sKs1);
    }
    if (hn1) { STG_B(2, nbuf, t + 1); STG_B(3, nbuf, t + 1); }
    __builtin_amdgcn_s_setprio(1);
#pragma unroll
    for (int il = 0; il < 4; ++il)
#pragma unroll
      for (int jl = 0; jl < 2; ++jl) {
        acc[il][2 + jl] = __builtin_amdgcn_mfma_f32_16x16x32_bf16(rAa[il][0], rB23[jl][0], acc[il][2 + jl], 0, 0, 0);
        acc[il][2 + jl] = __builtin_amdgcn_mfma_f32_16x16x32_bf16(rAa[il][1], rB23[jl][1], acc[il][2 + jl], 0, 0, 0);
      }
    __builtin_amdgcn_s_setprio(0);

    // ---- s2: drain reads + barrier (frees buf for t+2 A-stages); MFMA mq1 x nq0
    asm volatile("s_waitcnt lgkmcnt(0)" ::: "memory");
    BARRIER();
    SBAR();
    if (hn2) { STG_A(0, buf, t + 2); STG_A(1, buf, t + 2); }
    __builtin_amdgcn_s_setprio(1);
#pragma unroll
    for (int il = 0; il < 4; ++il)
#pragma unroll
      for (int jl = 0; jl < 2; ++jl) {
        acc[4 + il][jl] = __builtin_amdgcn_mfma_f32_16x16x32_bf16(rAb[il][0], rB01[jl][0], acc[4 + il][jl], 0, 0, 0);
        acc[4 + il][jl] = __builtin_amdgcn_mfma_f32_16x16x32_bf16(rAb[il][1], rB01[jl][1], acc[4 + il][jl], 0, 0, 0);
      }
    __builtin_amdgcn_s_setprio(0);

    // ---- s3: vmcnt+barrier (t+1 fully staged); stage A2,A3(t+2); read A02/B01(t+1); MFMA mq1 x nq1
    if (hn1) {
      if (hn2) asm volatile("s_waitcnt vmcnt(2)" ::: "memory");
      else     asm volatile("s_waitcnt vmcnt(0)" ::: "memory");
      BARRIER();
      SBAR();
      if (hn2) { STG_A(2, buf, t + 2); STG_A(3, buf, t + 2); }
#pragma unroll
      for (int il = 0; il < 4; ++il) {
        rAa[il][0] = *(const bf16x8*)(lbufN + aBase + il * 1024 + sKs0);
        rAa[il][1] = *(const bf16x8*)(lbufN + aBase + il * 1024 + sKs1);
      }
#pragma unroll
      for (int jl = 0; jl < 2; ++jl) {
        rB01[jl][0] = *(const bf16x8*)(lbufN + bBase + jl * 1024 + sKs0);
        rB01[jl][1] = *(const bf16x8*)(lbufN + bBase + jl * 1024 + sKs1);
      }
    }
    __builtin_amdgcn_s_setprio(1);
#pragma unroll
    for (int il = 0; il < 4; ++il)
#pragma unroll
      for (int jl = 0; jl < 2; ++jl) {
        acc[4 + il][2 + jl] = __builtin_amdgcn_mfma_f32_16x16x32_bf16(rAb[il][0], rB23[jl][0], acc[4 + il][2 + jl], 0, 0, 0);
        acc[4 + il][2 + jl] = __builtin_amdgcn_mfma_f32_16x16x32_bf16(rAb[il][1], rB23[jl][1], acc[4 + il][2 + jl], 0, 0, 0);
      }
    __builtin_amdgcn_s_setprio(0);
  }
#undef STG_A
#undef STG_B

  // --- epilogue ---
#pragma unroll
  for (int i = 0; i < 8; ++i) {
    int row_t = wm * 128 + i * 16 + fq * 4;
#pragma unroll
    for (int r = 0; r < 4; ++r) {
      int m = m0 + row_t + r;
      if (m >= cnt) continue;
      size_t rowoff = (size_t)(base + m) * (size_t)HS;
      if constexpr (PHASE == 0) {
        // h = silu(g) * u ; g = acc[i][jl], u = acc[i][2+jl], col = n0+wn*32+jl*16+fr
#pragma unroll
        for (int jl = 0; jl < 2; ++jl) {
          float g = acc[i][jl][r];
          float u = acc[i][2 + jl][r];
          float hval = (g / (1.f + __expf(-g))) * u;
          C1[rowoff + (n0 + wn * 32 + jl * 16 + fr)] = f2bf(hval);
        }
      } else {
#pragma unroll
        for (int j = 0; j < 4; ++j) {
          int col_t = n0 + wn * 64 + j * 16 + fr;
          float v = acc[i][j][r];
          if (shrd) OF[rowoff + col_t] = v;
          else      C1[rowoff + col_t] = f2bf(v);
        }
      }
    }
  }
}

// ---------------- y[t] += w0*yr[pos0] + w1*yr[pos1] ----------------
__global__ void k_combine(float* __restrict__ y, const u16* __restrict__ yr,
                          const float* __restrict__ tkw, const int* __restrict__ pos) {
  int t = blockIdx.x;
  int i = threadIdx.x;
  float w0 = tkw[2 * t], w1 = tkw[2 * t + 1];
  size_t p0 = (size_t)pos[2 * t] * DMODEL, p1 = (size_t)pos[2 * t + 1] * DMODEL;
  int d0 = i * 8;
  s16x8 a = *(const s16x8*)(yr + p0 + d0);
  s16x8 b = *(const s16x8*)(yr + p1 + d0);
  float* yo = y + (size_t)t * DMODEL + d0;
#pragma unroll
  for (int j = 0; j < 8; ++j)
    yo[j] += w0 * bf2f((u16)a[j]) + w1 * bf2f((u16)b[j]);
}

extern "C" void kernel_launch(void* const* d_in, const int* in_sizes, int n_in,
                              void* d_out, int out_size, void* d_ws, size_t ws_size,
                              hipStream_t stream) {
  const float* x   = (const float*)d_in[0];
  const float* gw  = (const float*)d_in[1];
  const float* wg  = (const float*)d_in[2];
  const float* wu  = (const float*)d_in[3];
  const float* wd  = (const float*)d_in[4];
  const float* wsg = (const float*)d_in[5];
  const float* wsu = (const float*)d_in[6];
  const float* wsd = (const float*)d_in[7];
  float* out = (float*)d_out;

  char* ws = (char*)d_ws;
  size_t o = 0;
  auto alloc = [&](size_t bytes) -> void* {
    void* p = ws + o;
    o += (bytes + 255) & ~(size_t)255;
    return p;
  };
  u16* xb   = (u16*)alloc((size_t)T_TOK * DMODEL * 2);
  u16* wbg  = (u16*)alloc((size_t)NEXP * DFF * DMODEL * 2);
  u16* wbu  = (u16*)alloc((size_t)NEXP * DFF * DMODEL * 2);
  u16* wbd  = (u16*)alloc((size_t)NEXP * DMODEL * DFF * 2);
  u16* wbsg = (u16*)alloc((size_t)DFFS * DMODEL * 2);
  u16* wbsu = (u16*)alloc((size_t)DFFS * DMODEL * 2);
  u16* wbsd = (u16*)alloc((size_t)DMODEL * DFFS * 2);
  u16* P1r  = (u16*)alloc((size_t)NSLOT * DFF * 2);    // h_r (silu fused in GU)
  u16* P1s  = (u16*)alloc((size_t)T_TOK * DFFS * 2);   // h_s
  u16* yr   = (u16*)alloc((size_t)NSLOT * DMODEL * 2);
  float* tkw = (float*)alloc((size_t)T_TOK * 2 * 4);
  int* tki   = (int*)alloc((size_t)T_TOK * 2 * 4);
  int* pos   = (int*)alloc((size_t)T_TOK * 2 * 4);
  int* slot_tok = (int*)alloc((size_t)NSLOT * 4);
  int* counts   = (int*)alloc(64);
  int* offs     = (int*)alloc(64);
  int* cursor   = (int*)alloc(64);
  int* tblGU    = (int*)alloc(GU_GRID * 4);
  int* tblDN    = (int*)alloc(DN_GRID * 4);
  int* nact     = (int*)alloc(64);
  if (o > ws_size) {
    fprintf(stderr, "kernel_launch: ws too small: need %zu have %zu\n", o, ws_size);
    return;
  }

  // --- routing (produces xb; gate/up weight converts backfilled) + schedule tables ---
  k_zero<<<1, 64, 0, stream>>>(counts);
  k_router<<<T_TOK + CONV_GU, 256, 0, stream>>>(x, gw, xb, tkw, tki, counts,
                                                wg, wbg, wu, wbu, wsg, wbsg, wsu, wbsu);
  k_scan_sched<<<1, 64, 0, stream>>>(counts, offs, cursor, tblGU, tblDN, nact);
  k_assign<<<(T_TOK + 255) / 256, 256, 0, stream>>>(tki, cursor, pos, slot_tok);

  // --- merged gate/up GEMM with fused silu (+ down-weight convert backfill) ---
  k_gemm8<0><<<GU_GRID + CONV_DN, 512, 0, stream>>>(
      tblGU, nact, xb, nullptr, nullptr,
      wbg, wbu, wbd, wbsg, wbsu, wbsd,
      wd, wsd, wbd, wbsd,
      P1r, P1s, yr, out, offs, counts, slot_tok);

  // --- merged down GEMM (routed -> yr, shared -> out) ---
  k_gemm8<1><<<DN_GRID, 512, 0, stream>>>(
      tblDN, nact, xb, P1r, P1s,
      wbg, wbu, wbd, wbsg, wbsu, wbsd,
      nullptr, nullptr, nullptr, nullptr,
      P1r, P1s, yr, out, offs, counts, slot_tok);

  // --- combine routed into output ---
  k_combine<<<T_TOK, 256, 0, stream>>>(out, yr, tkw, pos);
}